// Round 2
// baseline (1991.602 us; speedup 1.0000x reference)
//
#include <hip/hip_runtime.h>
#include <hip/hip_bf16.h>
#include <cstdint>
#include <cstddef>

using bf16 = __hip_bfloat16;
#define DEVFN static __device__ __forceinline__

constexpr int B = 4, V = 6, P = 200, C = 256, HH = 8, Dh = 32, NLEV = 4, NPTS = 4, FFN = 1024;
constexpr int L = 7441;
constexpr int BV = B * V, BP = B * P, BVP = B * V * P, BVL = B * V * L;
constexpr float IMG_W = 800.f, IMG_H = 448.f;

__constant__ int cLH[4] = {56, 28, 14, 7};
__constant__ int cLW[4] = {100, 50, 25, 13};
__constant__ int cLS[4] = {0, 5600, 7000, 7350};

// ---- workspace layout (offsets in floats) ----
constexpr size_t IRT   = 0;
constexpr size_t CAMT  = IRT + (size_t)BV * 16;
constexpr size_t MFLAG = CAMT + (size_t)BV * 3;
constexpr size_t Xo    = MFLAG + BV;
constexpr size_t QPOSo = Xo + (size_t)BP * C;
constexpr size_t Qo    = QPOSo + (size_t)BP * C;
constexpr size_t Ko    = Qo + (size_t)BP * C;
constexpr size_t VVo   = Ko + (size_t)BP * C;
constexpr size_t LOGo  = VVo + (size_t)BP * C;
constexpr size_t SAo   = LOGo + (size_t)B * HH * P * P;
constexpr size_t X1o   = SAo + (size_t)BVP * C;
constexpr size_t REFo  = X1o + (size_t)BVP * C;
constexpr size_t OFFo  = REFo + (size_t)BVP * 2;
constexpr size_t AWo   = OFFo + (size_t)BVP * 256;
constexpr size_t OUTSo = AWo + (size_t)BVP * 128;
constexpr size_t X2o   = OUTSo + (size_t)BVP * C;
constexpr size_t X3o   = X2o + (size_t)BVP * C;
constexpr size_t FUSEDo= X3o + (size_t)BVP * C;
constexpr size_t WS_FLOATS = FUSEDo + (size_t)BP * C;
constexpr size_t VALS_BYTE_OFF = ((WS_FLOATS * 4 + 255) / 256) * 256;

// ---- output layout (elements, f32) ----
constexpr size_t O0 = 0;                          // (B,C,P)
constexpr size_t O1 = O0 + (size_t)B * C * P;     // (B,P,3)
constexpr size_t O2 = O1 + (size_t)B * P * 3;     // (B,P,2)
constexpr size_t O3 = O2 + (size_t)B * P * 2;     // (B,2,P)
constexpr size_t O4 = O3 + (size_t)B * 2 * P;     // (B,1,P)

DEVFN float tof(bf16 x) { return __bfloat162float(x); }
DEVFN bf16  tobf(float x) { return __float2bfloat16(x); }

DEVFN float blockReduceSum(float v, float* red) {
    int j = threadIdx.x;
    __syncthreads();
    red[j] = v; __syncthreads();
    for (int s = 128; s > 0; s >>= 1) { if (j < s) red[j] += red[j + s]; __syncthreads(); }
    return red[0];
}
DEVFN float blockReduceMax(float v, float* red) {
    int j = threadIdx.x;
    __syncthreads();
    red[j] = v; __syncthreads();
    for (int s = 128; s > 0; s >>= 1) { if (j < s) red[j] = fmaxf(red[j], red[j + s]); __syncthreads(); }
    return red[0];
}

// out_j = sum_k s[k] * W[k*N + j]   (W f32 row-major (K,N), s in LDS)
DEVFN float dotK(const float* __restrict__ s, const float* __restrict__ W, int j, int N, int K) {
    float acc = 0.f;
    for (int k = 0; k < K; k += 4) {
        float4 h = *(const float4*)(s + k);
        acc += h.x * W[(size_t)(k + 0) * N + j];
        acc += h.y * W[(size_t)(k + 1) * N + j];
        acc += h.z * W[(size_t)(k + 2) * N + j];
        acc += h.w * W[(size_t)(k + 3) * N + j];
    }
    return acc;
}

// ---------------- setup: inverse(rt), cam_t, view-valid flag ----------------
__global__ __launch_bounds__(64) void k_setup(const float* rt, const float* l2cr, const float* l2ct,
                                              const int* maskin, float* ws) {
    int t = threadIdx.x;
    if (t >= BV) return;
    float m[16], inv[16];
    for (int i = 0; i < 16; i++) m[i] = rt[t * 16 + i];
    inv[0]  =  m[5]*m[10]*m[15] - m[5]*m[11]*m[14] - m[9]*m[6]*m[15] + m[9]*m[7]*m[14] + m[13]*m[6]*m[11] - m[13]*m[7]*m[10];
    inv[4]  = -m[4]*m[10]*m[15] + m[4]*m[11]*m[14] + m[8]*m[6]*m[15] - m[8]*m[7]*m[14] - m[12]*m[6]*m[11] + m[12]*m[7]*m[10];
    inv[8]  =  m[4]*m[9]*m[15]  - m[4]*m[11]*m[13] - m[8]*m[5]*m[15] + m[8]*m[7]*m[13] + m[12]*m[5]*m[11] - m[12]*m[7]*m[9];
    inv[12] = -m[4]*m[9]*m[14]  + m[4]*m[10]*m[13] + m[8]*m[5]*m[14] - m[8]*m[6]*m[13] - m[12]*m[5]*m[10] + m[12]*m[6]*m[9];
    inv[1]  = -m[1]*m[10]*m[15] + m[1]*m[11]*m[14] + m[9]*m[2]*m[15] - m[9]*m[3]*m[14] - m[13]*m[2]*m[11] + m[13]*m[3]*m[10];
    inv[5]  =  m[0]*m[10]*m[15] - m[0]*m[11]*m[14] - m[8]*m[2]*m[15] + m[8]*m[3]*m[14] + m[12]*m[2]*m[11] - m[12]*m[3]*m[10];
    inv[9]  = -m[0]*m[9]*m[15]  + m[0]*m[11]*m[13] + m[8]*m[1]*m[15] - m[8]*m[3]*m[13] - m[12]*m[1]*m[11] + m[12]*m[3]*m[9];
    inv[13] =  m[0]*m[9]*m[14]  - m[0]*m[10]*m[13] - m[8]*m[1]*m[14] + m[8]*m[2]*m[13] + m[12]*m[1]*m[10] - m[12]*m[2]*m[9];
    inv[2]  =  m[1]*m[6]*m[15]  - m[1]*m[7]*m[14]  - m[5]*m[2]*m[15] + m[5]*m[3]*m[14] + m[13]*m[2]*m[7]  - m[13]*m[3]*m[6];
    inv[6]  = -m[0]*m[6]*m[15]  + m[0]*m[7]*m[14]  + m[4]*m[2]*m[15] - m[4]*m[3]*m[14] - m[12]*m[2]*m[7]  + m[12]*m[3]*m[6];
    inv[10] =  m[0]*m[5]*m[15]  - m[0]*m[7]*m[13]  - m[4]*m[1]*m[15] + m[4]*m[3]*m[13] + m[12]*m[1]*m[7]  - m[12]*m[3]*m[5];
    inv[14] = -m[0]*m[5]*m[14]  + m[0]*m[6]*m[13]  + m[4]*m[1]*m[14] - m[4]*m[2]*m[13] - m[12]*m[1]*m[6]  + m[12]*m[2]*m[5];
    inv[3]  = -m[1]*m[6]*m[11]  + m[1]*m[7]*m[10]  + m[5]*m[2]*m[11] - m[5]*m[3]*m[10] - m[9]*m[2]*m[7]   + m[9]*m[3]*m[6];
    inv[7]  =  m[0]*m[6]*m[11]  - m[0]*m[7]*m[10]  - m[4]*m[2]*m[11] + m[4]*m[3]*m[10] + m[8]*m[2]*m[7]   - m[8]*m[3]*m[6];
    inv[11] = -m[0]*m[5]*m[11]  + m[0]*m[7]*m[9]   + m[4]*m[1]*m[11] - m[4]*m[3]*m[9]  - m[8]*m[1]*m[7]   + m[8]*m[3]*m[5];
    inv[15] =  m[0]*m[5]*m[10]  - m[0]*m[6]*m[9]   - m[4]*m[1]*m[10] + m[4]*m[2]*m[9]  + m[8]*m[1]*m[6]   - m[8]*m[2]*m[5];
    float det = m[0]*inv[0] + m[1]*inv[4] + m[2]*inv[8] + m[3]*inv[12];
    float rd = 1.f / det;
    for (int i = 0; i < 16; i++) ws[IRT + t * 16 + i] = inv[i] * rd;
    // cam_t_i = -sum_j r[j][i] * t[j]
    float r9[9], tv[3];
    for (int i = 0; i < 9; i++) r9[i] = l2cr[t * 9 + i];
    for (int i = 0; i < 3; i++) tv[i] = l2ct[t * 3 + i];
    for (int i = 0; i < 3; i++)
        ws[CAMT + t * 3 + i] = -(r9[0 * 3 + i] * tv[0] + r9[1 * 3 + i] * tv[1] + r9[2 * 3 + i] * tv[2]);
    int b = t / V, v = t % V, cnt = 0;
    for (int p = 0; p < P; p++) cnt += (maskin[(b * P + p) * V + v] > 0) ? 1 : 0;
    ws[MFLAG + t] = (cnt > 1) ? 1.f : 0.f;
}

// ---------------- qpos MLP + x transpose ----------------
__global__ __launch_bounds__(256) void k_qpos(const float* qfeat, const float* qposin,
                                              const float* w1, const float* b1, const float* w2, const float* b2,
                                              float* ws) {
    int row = blockIdx.x, j = threadIdx.x;
    int b = row / P, p = row % P;
    __shared__ __align__(16) float pos[4];
    __shared__ __align__(16) float hid[C];
    if (j < 3) pos[j] = qposin[row * 3 + j];
    __syncthreads();
    float h = b1[j] + pos[0] * w1[0 * C + j] + pos[1] * w1[1 * C + j] + pos[2] * w1[2 * C + j];
    hid[j] = fmaxf(h, 0.f);
    __syncthreads();
    float acc = b2[j] + dotK(hid, w2, j, C, C);
    ws[QPOSo + (size_t)row * C + j] = acc;
    ws[Xo + (size_t)row * C + j] = qfeat[((size_t)b * C + j) * P + p];
}

// ---------------- q / k / v projections ----------------
__global__ __launch_bounds__(256) void k_qkv(const float* wq, const float* wk, const float* wv, float* ws) {
    int row = blockIdx.x, which = blockIdx.y, j = threadIdx.x;
    __shared__ __align__(16) float in[C];
    float xv = ws[Xo + (size_t)row * C + j];
    in[j] = (which < 2) ? (xv + ws[QPOSo + (size_t)row * C + j]) : xv;
    __syncthreads();
    const float* W = (which == 0) ? wq : (which == 1) ? wk : wv;
    float acc = dotK(in, W, j, C, C);
    size_t dst = (which == 0) ? Qo : (which == 1) ? Ko : VVo;
    ws[dst + (size_t)row * C + j] = acc;
}

// ---------------- attention logits (mask-independent) ----------------
__global__ __launch_bounds__(256) void k_logits(float* ws) {
    int bid = blockIdx.x;          // (b*HH + h)*P + qi
    int qi = bid % P, h = (bid / P) % HH, b = bid / (P * HH);
    int j = threadIdx.x;
    __shared__ __align__(16) float qf[Dh];
    if (j < Dh) qf[j] = ws[Qo + ((size_t)(b * P + qi)) * C + h * Dh + j];
    __syncthreads();
    if (j < P) {
        const float* kp = ws + Ko + ((size_t)(b * P + j)) * C + h * Dh;
        float acc = 0.f;
        for (int d = 0; d < Dh; d += 4) {
            float4 kv = *(const float4*)(kp + d);
            float4 qv = *(const float4*)(qf + d);
            acc += kv.x * qv.x + kv.y * qv.y + kv.z * qv.z + kv.w * qv.w;
        }
        ws[LOGo + (size_t)bid * P + j] = acc * 0.17677669529663687f;  // 1/sqrt(32)
    }
}

// ---------------- masked softmax + attn @ V ----------------
__global__ __launch_bounds__(256) void k_sattn(const int* maskin, float* ws) {
    int bid = blockIdx.x;          // ((b*V+v)*HH + h)*P + qi
    int qi = bid % P, h = (bid / P) % HH, v = (bid / (P * HH)) % V, b = bid / (P * HH * V);
    int j = threadIdx.x;
    __shared__ float attn[256];
    __shared__ float red[256];
    float flag = ws[MFLAG + b * V + v];
    float val = -1e30f;
    if (j < P) {
        float lg = ws[LOGo + ((size_t)(b * HH + h) * P + qi) * P + j];
        bool mk = (flag > 0.5f) && (maskin[(b * P + j) * V + v] > 0);
        val = lg + (mk ? 0.f : -1e9f);
    }
    float mx = blockReduceMax(val, red);
    float e = (j < P) ? __expf(val - mx) : 0.f;
    float s = blockReduceSum(e, red);
    attn[j] = e / s;
    __syncthreads();
    int d = j & 31, c = j >> 5;                 // 8 chunks of 25 keys
    const float* vvp = ws + VVo + (size_t)b * P * C + h * Dh + d;
    float acc = 0.f;
    for (int kk = c * 25; kk < c * 25 + 25; ++kk) acc += attn[kk] * vvp[(size_t)kk * C];
    red[j] = acc; __syncthreads();
    if (j < Dh) {
        float s2 = 0.f;
        for (int c2 = 0; c2 < 8; c2++) s2 += red[c2 * 32 + j];
        ws[SAo + ((size_t)((b * V + v) * P + qi)) * C + h * Dh + j] = s2;
    }
}

// ---------------- sa @ wo + residual + LN -> x1 ----------------
__global__ __launch_bounds__(256) void k_saout(const float* wo, float* ws) {
    int row = blockIdx.x, j = threadIdx.x;    // row over (b,v,p)
    int p = row % P, b = row / (P * V);
    __shared__ __align__(16) float in[C];
    __shared__ float red[256];
    in[j] = ws[SAo + (size_t)row * C + j];
    __syncthreads();
    float t = dotK(in, wo, j, C, C);
    float r = ws[Xo + ((size_t)(b * P + p)) * C + j] + t;
    float mean = blockReduceSum(r, red) * (1.f / C);
    float diff = r - mean;
    float var = blockReduceSum(diff * diff, red) * (1.f / C);
    ws[X1o + (size_t)row * C + j] = diff * rsqrtf(var + 1e-5f);
}

// ---------------- reference points ----------------
__global__ __launch_bounds__(256) void k_ref(const float* qposin, const float* rt, float* ws) {
    int tid = blockIdx.x * 256 + threadIdx.x;
    if (tid >= BVP) return;
    int p = tid % P, v = (tid / P) % V, b = tid / (P * V);
    float p0 = qposin[(b * P + p) * 3 + 0];
    float p1 = qposin[(b * P + p) * 3 + 1];
    float p2 = qposin[(b * P + p) * 3 + 2];
    const float* m = rt + (size_t)(b * V + v) * 16;
    float pr[3];
    for (int i = 0; i < 3; i++)
        pr[i] = m[i * 4 + 0] * p0 + m[i * 4 + 1] * p1 + m[i * 4 + 2] * p2 + m[i * 4 + 3];
    ws[REFo + (size_t)tid * 2 + 0] = pr[0] / pr[2] / IMG_W;
    ws[REFo + (size_t)tid * 2 + 1] = pr[1] / pr[2] / IMG_H;
}

// ---------------- offsets + attention weights heads ----------------
__global__ __launch_bounds__(256) void k_offaw(const float* ow, const float* ob, const float* aw_w, const float* aw_b,
                                               float* ws) {
    int row = blockIdx.x, j = threadIdx.x;    // row over (b,v,p)
    int p = row % P, b = row / (P * V);
    __shared__ __align__(16) float q2[C];
    __shared__ float al[128];
    q2[j] = ws[X1o + (size_t)row * C + j] + ws[QPOSo + ((size_t)(b * P + p)) * C + j];
    __syncthreads();
    float offv = ob[j] + dotK(q2, ow, j, 256, C);
    ws[OFFo + (size_t)row * 256 + j] = offv;
    if (j < 128) al[j] = aw_b[j] + dotK(q2, aw_w, j, 128, C);
    __syncthreads();
    if (j < 128) {
        int g = (j >> 4) << 4;
        float mx = -1e30f;
        for (int i = 0; i < 16; i++) mx = fmaxf(mx, al[g + i]);
        float s = 0.f;
        for (int i = 0; i < 16; i++) s += __expf(al[g + i] - mx);
        ws[AWo + (size_t)row * 128 + j] = __expf(al[j] - mx) / s;
    }
}

// ---------------- vals = (feat^T + kpos_mlp) @ dv_w ----------------
constexpr int TILE = 16;
__global__ __launch_bounds__(256) void k_vals(const float* npos, const float* feats,
                                              const float* kw1, const float* kb1, const float* kw2, const float* kb2,
                                              const float* dvw, const float* ws, bf16* vals) {
    int j = threadIdx.x;
    int r0 = blockIdx.x * TILE;
    __shared__ float kp6[TILE][8];
    __shared__ int rowIdx[TILE];
    __shared__ int rowL[TILE];
    __shared__ int rowOK[TILE];
    __shared__ __align__(16) float hid[TILE][C];
    __shared__ __align__(16) float vin[TILE][C];
    if (j < TILE) {
        int r = r0 + j;
        int ok = (r < BVL) ? 1 : 0;
        int rr = ok ? r : 0;
        int bv = rr / L, l = rr % L;
        rowIdx[j] = bv; rowL[j] = l; rowOK[j] = ok;
        float sx = 1.f / (1.f + __expf(-npos[l * 2 + 0])) * IMG_W;
        float sy = 1.f / (1.f + __expf(-npos[l * 2 + 1])) * IMG_H;
        const float* inv = ws + IRT + (size_t)bv * 16;
        for (int i = 0; i < 3; i++)
            kp6[j][i] = inv[i * 4 + 0] * sx + inv[i * 4 + 1] * sy + inv[i * 4 + 2] + inv[i * 4 + 3];
        for (int i = 0; i < 3; i++) kp6[j][3 + i] = ws[CAMT + (size_t)bv * 3 + i];
    }
    __syncthreads();
    {   // hidden = relu(kp6 @ kw1 + kb1)
        float w1j[6];
        for (int k2 = 0; k2 < 6; k2++) w1j[k2] = kw1[k2 * C + j];
        float bb = kb1[j];
        for (int r = 0; r < TILE; r++) {
            float h = bb;
            for (int k2 = 0; k2 < 6; k2++) h += kp6[r][k2] * w1j[k2];
            hid[r][j] = fmaxf(h, 0.f);
        }
    }
    __syncthreads();
    {   // kemb = hidden @ kw2 + kb2 ; vin = kemb + feat
        float acc[TILE];
        float bb = kb2[j];
        for (int r = 0; r < TILE; r++) acc[r] = bb;
        for (int k = 0; k < C; k += 4) {
            float w0 = kw2[(size_t)(k + 0) * C + j];
            float w1 = kw2[(size_t)(k + 1) * C + j];
            float w2 = kw2[(size_t)(k + 2) * C + j];
            float w3 = kw2[(size_t)(k + 3) * C + j];
            for (int r = 0; r < TILE; r++) {
                float4 h4 = *(const float4*)&hid[r][k];
                acc[r] += h4.x * w0 + h4.y * w1 + h4.z * w2 + h4.w * w3;
            }
        }
        for (int r = 0; r < TILE; r++) {
            float fv = 0.f;
            if (rowOK[r]) fv = feats[((size_t)rowIdx[r] * C + j) * L + rowL[r]];
            vin[r][j] = acc[r] + fv;
        }
    }
    __syncthreads();
    {   // vals = vin @ dvw
        float acc[TILE];
        for (int r = 0; r < TILE; r++) acc[r] = 0.f;
        for (int k = 0; k < C; k += 4) {
            float w0 = dvw[(size_t)(k + 0) * C + j];
            float w1 = dvw[(size_t)(k + 1) * C + j];
            float w2 = dvw[(size_t)(k + 2) * C + j];
            float w3 = dvw[(size_t)(k + 3) * C + j];
            for (int r = 0; r < TILE; r++) {
                float4 h4 = *(const float4*)&vin[r][k];
                acc[r] += h4.x * w0 + h4.y * w1 + h4.z * w2 + h4.w * w3;
            }
        }
        for (int r = 0; r < TILE; r++)
            if (rowOK[r]) vals[(size_t)(r0 + r) * C + j] = tobf(acc[r]);
    }
}

// ---------------- deformable bilinear sampling + weighted sum ----------------
__global__ __launch_bounds__(256) void k_sample(const float* ws, const bf16* vals, float* wsmut) {
    int row = blockIdx.x, j = threadIdx.x;   // row over (b,v,p); thread = (h, d)
    int h = j >> 5, d = j & 31;
    __shared__ float soff[256];
    __shared__ float sawL[128];
    __shared__ float sref[2];
    soff[j] = ws[OFFo + (size_t)row * 256 + j];
    if (j < 128) sawL[j] = ws[AWo + (size_t)row * 128 + j];
    if (j < 2) sref[j] = ws[REFo + (size_t)row * 2 + j];
    __syncthreads();
    int v = (row / P) % V, b = row / (P * V);
    const bf16* vbase = vals + (size_t)(b * V + v) * L * C + h * Dh + d;
    float acc = 0.f;
    for (int l = 0; l < NLEV; l++) {
        float Wf = (float)cLW[l], Hf = (float)cLH[l];
        int Wi = cLW[l], Hi = cLH[l], S0 = cLS[l];
        for (int n = 0; n < NPTS; n++) {
            int oi = ((h * NLEV + l) * NPTS + n) * 2;
            float lx = sref[0] + soff[oi + 0] / Wf;
            float ly = sref[1] + soff[oi + 1] / Hf;
            float aww = sawL[(h * NLEV + l) * NPTS + n];
            float x = lx * Wf - 0.5f, y = ly * Hf - 0.5f;
            float x0f = floorf(x), y0f = floorf(y);
            float wx = x - x0f, wy = y - y0f;
            int x0 = (int)x0f, y0 = (int)y0f;
            float s = 0.f;
            #pragma unroll
            for (int dy = 0; dy < 2; dy++) {
                #pragma unroll
                for (int dx = 0; dx < 2; dx++) {
                    int xi = x0 + dx, yi = y0 + dy;
                    if (xi >= 0 && xi < Wi && yi >= 0 && yi < Hi) {
                        float wwt = (dx ? wx : 1.f - wx) * (dy ? wy : 1.f - wy);
                        s += wwt * tof(vbase[(size_t)(S0 + yi * Wi + xi) * C]);
                    }
                }
            }
            acc += aww * s;
        }
    }
    wsmut[OUTSo + (size_t)row * C + j] = acc;   // c = h*32+d = j
}

// ---------------- out @ dout_w + x1 + LN -> x2 ----------------
__global__ __launch_bounds__(256) void k_dout(const float* dw, float* ws) {
    int row = blockIdx.x, j = threadIdx.x;
    __shared__ __align__(16) float in[C];
    __shared__ float red[256];
    in[j] = ws[OUTSo + (size_t)row * C + j];
    __syncthreads();
    float t = dotK(in, dw, j, C, C);
    float r = ws[X1o + (size_t)row * C + j] + t;
    float mean = blockReduceSum(r, red) * (1.f / C);
    float diff = r - mean;
    float var = blockReduceSum(diff * diff, red) * (1.f / C);
    ws[X2o + (size_t)row * C + j] = diff * rsqrtf(var + 1e-5f);
}

// ---------------- FFN + LN -> x3 ----------------
__global__ __launch_bounds__(256) void k_ffn(const float* w1, const float* b1, const float* w2, const float* b2,
                                             float* ws) {
    int row = blockIdx.x, j = threadIdx.x;
    __shared__ __align__(16) float in[C];
    __shared__ __align__(16) float hid[FFN];
    __shared__ float red[256];
    float xv = ws[X2o + (size_t)row * C + j];
    in[j] = xv;
    __syncthreads();
    for (int u = 0; u < 4; u++) {
        int jj = j + u * 256;
        float acc = b1[jj];
        for (int k = 0; k < C; k += 4) {
            float4 h = *(const float4*)&in[k];
            acc += h.x * w1[(size_t)(k + 0) * FFN + jj];
            acc += h.y * w1[(size_t)(k + 1) * FFN + jj];
            acc += h.z * w1[(size_t)(k + 2) * FFN + jj];
            acc += h.w * w1[(size_t)(k + 3) * FFN + jj];
        }
        hid[jj] = fmaxf(acc, 0.f);
    }
    __syncthreads();
    float acc = b2[j] + dotK(hid, w2, j, C, FFN);
    float r = xv + acc;
    float mean = blockReduceSum(r, red) * (1.f / C);
    float diff = r - mean;
    float var = blockReduceSum(diff * diff, red) * (1.f / C);
    ws[X3o + (size_t)row * C + j] = diff * rsqrtf(var + 1e-5f);
}

// ---------------- masked view-mean + output0 ----------------
__global__ __launch_bounds__(256) void k_fuse(const int* maskin, float* ws, float* out) {
    int row = blockIdx.x, j = threadIdx.x;   // row over (b,p)
    int b = row / P, p = row % P;
    float s = 0.f, cnt = 0.f;
    for (int v = 0; v < V; v++) {
        bool mk = (maskin[(b * P + p) * V + v] > 0) && (ws[MFLAG + b * V + v] > 0.5f);
        if (mk) {
            s += ws[X3o + ((size_t)((b * V + v) * P + p)) * C + j];
            cnt += 1.f;
        }
    }
    float f = s / (cnt + 1e-4f);
    ws[FUSEDo + (size_t)row * C + j] = f;
    out[O0 + ((size_t)b * C + j) * P + p] = f;
}

// ---------------- pred head + BEV outputs ----------------
__global__ __launch_bounds__(256) void k_pred(const float* w1, const float* b1, const float* w2, const float* b2,
                                              const float* qposin, float* ws, float* out) {
    int row = blockIdx.x, j = threadIdx.x;   // row over (b,p)
    __shared__ __align__(16) float in[C];
    __shared__ float red[256];
    __shared__ float cen[4];
    in[j] = ws[FUSEDo + (size_t)row * C + j];
    __syncthreads();
    float h = fmaxf(b1[j] + dotK(in, w1, j, C, C), 0.f);
    for (int i = 0; i < 3; i++) {
        float s = blockReduceSum(h * w2[j * 3 + i], red);
        if (j == 0) cen[i] = s + b2[i] + qposin[row * 3 + i];
    }
    if (j == 0) {
        float c0 = cen[0], c1 = cen[1], c2 = cen[2];
        float cx = (c0 + 54.f) / 108.f * 135.f;
        float cy = (c1 + 54.f) / 108.f * 135.f;
        int b = row / P, p = row % P;
        out[O1 + (size_t)row * 3 + 0] = c0;
        out[O1 + (size_t)row * 3 + 1] = c1;
        out[O1 + (size_t)row * 3 + 2] = c2;
        out[O2 + (size_t)row * 2 + 0] = cx;
        out[O2 + (size_t)row * 2 + 1] = cy;
        out[O3 + (size_t)b * 2 * P + 0 * P + p] = cx;
        out[O3 + (size_t)b * 2 * P + 1 * P + p] = cy;
        out[O4 + (size_t)b * P + p] = c2;
    }
}

extern "C" void kernel_launch(void* const* d_in, const int* in_sizes, int n_in,
                              void* d_out, int out_size, void* d_ws, size_t ws_size,
                              hipStream_t stream) {
    const float* qfeat  = (const float*)d_in[0];
    const float* qposin = (const float*)d_in[1];
    const int*   maskin = (const int*)d_in[2];
    const float* feats  = (const float*)d_in[3];
    const float* npos   = (const float*)d_in[4];
    const float* rt     = (const float*)d_in[5];
    const float* l2cr   = (const float*)d_in[6];
    const float* l2ct   = (const float*)d_in[7];
    const float* qp_w1 = (const float*)d_in[8],  * qp_b1 = (const float*)d_in[9];
    const float* qp_w2 = (const float*)d_in[10], * qp_b2 = (const float*)d_in[11];
    const float* kp_w1 = (const float*)d_in[12], * kp_b1 = (const float*)d_in[13];
    const float* kp_w2 = (const float*)d_in[14], * kp_b2 = (const float*)d_in[15];
    const float* sa_wq = (const float*)d_in[16], * sa_wk = (const float*)d_in[17];
    const float* sa_wv = (const float*)d_in[18], * sa_wo = (const float*)d_in[19];
    const float* dv_w  = (const float*)d_in[20];
    const float* doffw = (const float*)d_in[21], * doffb = (const float*)d_in[22];
    const float* dattw = (const float*)d_in[23], * dattb = (const float*)d_in[24];
    const float* doutw = (const float*)d_in[25];
    const float* f_w1  = (const float*)d_in[26], * f_b1 = (const float*)d_in[27];
    const float* f_w2  = (const float*)d_in[28], * f_b2 = (const float*)d_in[29];
    const float* p_w1  = (const float*)d_in[30], * p_b1 = (const float*)d_in[31];
    const float* p_w2  = (const float*)d_in[32], * p_b2 = (const float*)d_in[33];

    float* ws = (float*)d_ws;
    bf16* vals = (bf16*)((char*)d_ws + VALS_BYTE_OFF);
    float* out = (float*)d_out;

    k_setup<<<1, 64, 0, stream>>>(rt, l2cr, l2ct, maskin, ws);
    k_qpos<<<BP, 256, 0, stream>>>(qfeat, qposin, qp_w1, qp_b1, qp_w2, qp_b2, ws);
    k_qkv<<<dim3(BP, 3), 256, 0, stream>>>(sa_wq, sa_wk, sa_wv, ws);
    k_logits<<<B * HH * P, 256, 0, stream>>>(ws);
    k_sattn<<<B * V * HH * P, 256, 0, stream>>>(maskin, ws);
    k_saout<<<BVP, 256, 0, stream>>>(sa_wo, ws);
    k_ref<<<(BVP + 255) / 256, 256, 0, stream>>>(qposin, rt, ws);
    k_offaw<<<BVP, 256, 0, stream>>>(doffw, doffb, dattw, dattb, ws);
    k_vals<<<(BVL + TILE - 1) / TILE, 256, 0, stream>>>(npos, feats, kp_w1, kp_b1, kp_w2, kp_b2, dv_w, ws, vals);
    k_sample<<<BVP, 256, 0, stream>>>(ws, vals, ws);
    k_dout<<<BVP, 256, 0, stream>>>(doutw, ws);
    k_ffn<<<BVP, 256, 0, stream>>>(f_w1, f_b1, f_w2, f_b2, ws);
    k_fuse<<<BP, 256, 0, stream>>>(maskin, ws, out);
    k_pred<<<BP, 256, 0, stream>>>(p_w1, p_b1, p_w2, p_b2, qposin, ws, out);
}

// Round 3
// 1376.444 us; speedup vs baseline: 1.4469x; 1.4469x over previous
//
#include <hip/hip_runtime.h>
#include <hip/hip_bf16.h>
#include <cstdint>
#include <cstddef>

using bf16 = __hip_bfloat16;
#define DEVFN static __device__ __forceinline__

constexpr int B = 4, V = 6, P = 200, C = 256, HH = 8, Dh = 32, NLEV = 4, NPTS = 4, FFN = 1024;
constexpr int L = 7441;
constexpr int BV = B * V, BP = B * P, BVP = B * V * P, BVL = B * V * L;
constexpr float IMG_W = 800.f, IMG_H = 448.f;

__constant__ int cLH[4] = {56, 28, 14, 7};
__constant__ int cLW[4] = {100, 50, 25, 13};
__constant__ int cLS[4] = {0, 5600, 7000, 7350};

// ---- workspace layout (offsets in floats) ----
constexpr size_t IRT   = 0;
constexpr size_t CAMT  = IRT + (size_t)BV * 16;
constexpr size_t MFLAG = CAMT + (size_t)BV * 3;
constexpr size_t Xo    = MFLAG + BV;
constexpr size_t QPOSo = Xo + (size_t)BP * C;
constexpr size_t Qo    = QPOSo + (size_t)BP * C;
constexpr size_t Ko    = Qo + (size_t)BP * C;
constexpr size_t VVo   = Ko + (size_t)BP * C;
constexpr size_t LOGo  = VVo + (size_t)BP * C;
constexpr size_t SAo   = LOGo + (size_t)B * HH * P * P;
constexpr size_t X1o   = SAo + (size_t)BVP * C;
constexpr size_t REFo  = X1o + (size_t)BVP * C;
constexpr size_t OFFo  = REFo + (size_t)BVP * 2;
constexpr size_t AWo   = OFFo + (size_t)BVP * 256;
constexpr size_t OUTSo = AWo + (size_t)BVP * 128;
constexpr size_t X2o   = OUTSo + (size_t)BVP * C;
constexpr size_t X3o   = X2o + (size_t)BVP * C;
constexpr size_t FUSEDo= X3o + (size_t)BVP * C;
constexpr size_t WS_FLOATS = FUSEDo + (size_t)BP * C;
constexpr size_t VALS_BYTE_OFF = ((WS_FLOATS * 4 + 255) / 256) * 256;
constexpr size_t VALS_ELEMS = (size_t)BVL * C;   // bf16

// ---- output layout (elements, f32) ----
constexpr size_t O0 = 0;                          // (B,C,P)
constexpr size_t O1 = O0 + (size_t)B * C * P;     // (B,P,3)
constexpr size_t O2 = O1 + (size_t)B * P * 3;     // (B,P,2)
constexpr size_t O3 = O2 + (size_t)B * P * 2;     // (B,2,P)
constexpr size_t O4 = O3 + (size_t)B * 2 * P;     // (B,1,P)

DEVFN float tof(bf16 x) { return __bfloat162float(x); }
DEVFN bf16  tobf(float x) { return __float2bfloat16(x); }

typedef __attribute__((ext_vector_type(8))) short short8;
typedef __attribute__((ext_vector_type(4))) float floatx4;

DEVFN float blockReduceSum(float v, float* red) {
    int j = threadIdx.x;
    __syncthreads();
    red[j] = v; __syncthreads();
    for (int s = 128; s > 0; s >>= 1) { if (j < s) red[j] += red[j + s]; __syncthreads(); }
    return red[0];
}
DEVFN float blockReduceMax(float v, float* red) {
    int j = threadIdx.x;
    __syncthreads();
    red[j] = v; __syncthreads();
    for (int s = 128; s > 0; s >>= 1) { if (j < s) red[j] = fmaxf(red[j], red[j + s]); __syncthreads(); }
    return red[0];
}

// out_j = sum_k s[k] * W[k*N + j]   (W f32 row-major (K,N), s in LDS)
DEVFN float dotK(const float* __restrict__ s, const float* __restrict__ W, int j, int N, int K) {
    float acc = 0.f;
    for (int k = 0; k < K; k += 4) {
        float4 h = *(const float4*)(s + k);
        acc += h.x * W[(size_t)(k + 0) * N + j];
        acc += h.y * W[(size_t)(k + 1) * N + j];
        acc += h.z * W[(size_t)(k + 2) * N + j];
        acc += h.w * W[(size_t)(k + 3) * N + j];
    }
    return acc;
}

// ---------------- setup: inverse(rt), cam_t, view-valid flag ----------------
__global__ __launch_bounds__(64) void k_setup(const float* rt, const float* l2cr, const float* l2ct,
                                              const int* maskin, float* ws) {
    int t = threadIdx.x;
    if (t >= BV) return;
    float m[16], inv[16];
    for (int i = 0; i < 16; i++) m[i] = rt[t * 16 + i];
    inv[0]  =  m[5]*m[10]*m[15] - m[5]*m[11]*m[14] - m[9]*m[6]*m[15] + m[9]*m[7]*m[14] + m[13]*m[6]*m[11] - m[13]*m[7]*m[10];
    inv[4]  = -m[4]*m[10]*m[15] + m[4]*m[11]*m[14] + m[8]*m[6]*m[15] - m[8]*m[7]*m[14] - m[12]*m[6]*m[11] + m[12]*m[7]*m[10];
    inv[8]  =  m[4]*m[9]*m[15]  - m[4]*m[11]*m[13] - m[8]*m[5]*m[15] + m[8]*m[7]*m[13] + m[12]*m[5]*m[11] - m[12]*m[7]*m[9];
    inv[12] = -m[4]*m[9]*m[14]  + m[4]*m[10]*m[13] + m[8]*m[5]*m[14] - m[8]*m[6]*m[13] - m[12]*m[5]*m[10] + m[12]*m[6]*m[9];
    inv[1]  = -m[1]*m[10]*m[15] + m[1]*m[11]*m[14] + m[9]*m[2]*m[15] - m[9]*m[3]*m[14] - m[13]*m[2]*m[11] + m[13]*m[3]*m[10];
    inv[5]  =  m[0]*m[10]*m[15] - m[0]*m[11]*m[14] - m[8]*m[2]*m[15] + m[8]*m[3]*m[14] + m[12]*m[2]*m[11] - m[12]*m[3]*m[10];
    inv[9]  = -m[0]*m[9]*m[15]  + m[0]*m[11]*m[13] + m[8]*m[1]*m[15] - m[8]*m[3]*m[13] - m[12]*m[1]*m[11] + m[12]*m[3]*m[9];
    inv[13] =  m[0]*m[9]*m[14]  - m[0]*m[10]*m[13] - m[8]*m[1]*m[14] + m[8]*m[2]*m[13] + m[12]*m[1]*m[10] - m[12]*m[2]*m[9];
    inv[2]  =  m[1]*m[6]*m[15]  - m[1]*m[7]*m[14]  - m[5]*m[2]*m[15] + m[5]*m[3]*m[14] + m[13]*m[2]*m[7]  - m[13]*m[3]*m[6];
    inv[6]  = -m[0]*m[6]*m[15]  + m[0]*m[7]*m[14]  + m[4]*m[2]*m[15] - m[4]*m[3]*m[14] - m[12]*m[2]*m[7]  + m[12]*m[3]*m[6];
    inv[10] =  m[0]*m[5]*m[15]  - m[0]*m[7]*m[13]  - m[4]*m[1]*m[15] + m[4]*m[3]*m[13] + m[12]*m[1]*m[7]  - m[12]*m[3]*m[5];
    inv[14] = -m[0]*m[5]*m[14]  + m[0]*m[6]*m[13]  + m[4]*m[1]*m[14] - m[4]*m[2]*m[13] - m[12]*m[1]*m[6]  + m[12]*m[2]*m[5];
    inv[3]  = -m[1]*m[6]*m[11]  + m[1]*m[7]*m[10]  + m[5]*m[2]*m[11] - m[5]*m[3]*m[10] - m[9]*m[2]*m[7]   + m[9]*m[3]*m[6];
    inv[7]  =  m[0]*m[6]*m[11]  - m[0]*m[7]*m[10]  - m[4]*m[2]*m[11] + m[4]*m[3]*m[10] + m[8]*m[2]*m[7]   - m[8]*m[3]*m[6];
    inv[11] = -m[0]*m[5]*m[11]  + m[0]*m[7]*m[9]   + m[4]*m[1]*m[11] - m[4]*m[3]*m[9]  - m[8]*m[1]*m[7]   + m[8]*m[3]*m[5];
    inv[15] =  m[0]*m[5]*m[10]  - m[0]*m[6]*m[9]   - m[4]*m[1]*m[10] + m[4]*m[2]*m[9]  + m[8]*m[1]*m[6]   - m[8]*m[2]*m[5];
    float det = m[0]*inv[0] + m[1]*inv[4] + m[2]*inv[8] + m[3]*inv[12];
    float rd = 1.f / det;
    for (int i = 0; i < 16; i++) ws[IRT + t * 16 + i] = inv[i] * rd;
    float r9[9], tv[3];
    for (int i = 0; i < 9; i++) r9[i] = l2cr[t * 9 + i];
    for (int i = 0; i < 3; i++) tv[i] = l2ct[t * 3 + i];
    for (int i = 0; i < 3; i++)
        ws[CAMT + t * 3 + i] = -(r9[0 * 3 + i] * tv[0] + r9[1 * 3 + i] * tv[1] + r9[2 * 3 + i] * tv[2]);
    int b = t / V, v = t % V, cnt = 0;
    for (int p = 0; p < P; p++) cnt += (maskin[(b * P + p) * V + v] > 0) ? 1 : 0;
    ws[MFLAG + t] = (cnt > 1) ? 1.f : 0.f;
}

// ---------------- weight prep: transpose + bf16 cast for MFMA B operands ----------------
__global__ __launch_bounds__(256) void k_wprep(const float* kw2, const float* dvw, bf16* kw2T, bf16* dvwT) {
    int n = blockIdx.x & 255;
    int k = threadIdx.x;
    if (blockIdx.x < 256) kw2T[n * 256 + k] = tobf(kw2[(size_t)k * 256 + n]);
    else                  dvwT[n * 256 + k] = tobf(dvw[(size_t)k * 256 + n]);
}

// ---------------- qpos MLP + x transpose ----------------
__global__ __launch_bounds__(256) void k_qpos(const float* qfeat, const float* qposin,
                                              const float* w1, const float* b1, const float* w2, const float* b2,
                                              float* ws) {
    int row = blockIdx.x, j = threadIdx.x;
    int b = row / P, p = row % P;
    __shared__ __align__(16) float pos[4];
    __shared__ __align__(16) float hid[C];
    if (j < 3) pos[j] = qposin[row * 3 + j];
    __syncthreads();
    float h = b1[j] + pos[0] * w1[0 * C + j] + pos[1] * w1[1 * C + j] + pos[2] * w1[2 * C + j];
    hid[j] = fmaxf(h, 0.f);
    __syncthreads();
    float acc = b2[j] + dotK(hid, w2, j, C, C);
    ws[QPOSo + (size_t)row * C + j] = acc;
    ws[Xo + (size_t)row * C + j] = qfeat[((size_t)b * C + j) * P + p];
}

// ---------------- q / k / v projections ----------------
__global__ __launch_bounds__(256) void k_qkv(const float* wq, const float* wk, const float* wv, float* ws) {
    int row = blockIdx.x, which = blockIdx.y, j = threadIdx.x;
    __shared__ __align__(16) float in[C];
    float xv = ws[Xo + (size_t)row * C + j];
    in[j] = (which < 2) ? (xv + ws[QPOSo + (size_t)row * C + j]) : xv;
    __syncthreads();
    const float* W = (which == 0) ? wq : (which == 1) ? wk : wv;
    float acc = dotK(in, W, j, C, C);
    size_t dst = (which == 0) ? Qo : (which == 1) ? Ko : VVo;
    ws[dst + (size_t)row * C + j] = acc;
}

// ---------------- attention logits ----------------
__global__ __launch_bounds__(256) void k_logits(float* ws) {
    int bid = blockIdx.x;          // (b*HH + h)*P + qi
    int qi = bid % P, h = (bid / P) % HH, b = bid / (P * HH);
    int j = threadIdx.x;
    __shared__ __align__(16) float qf[Dh];
    if (j < Dh) qf[j] = ws[Qo + ((size_t)(b * P + qi)) * C + h * Dh + j];
    __syncthreads();
    if (j < P) {
        const float* kp = ws + Ko + ((size_t)(b * P + j)) * C + h * Dh;
        float acc = 0.f;
        for (int d = 0; d < Dh; d += 4) {
            float4 kv = *(const float4*)(kp + d);
            float4 qv = *(const float4*)(qf + d);
            acc += kv.x * qv.x + kv.y * qv.y + kv.z * qv.z + kv.w * qv.w;
        }
        ws[LOGo + (size_t)bid * P + j] = acc * 0.17677669529663687f;
    }
}

// ---------------- masked softmax + attn @ V ----------------
__global__ __launch_bounds__(256) void k_sattn(const int* maskin, float* ws) {
    int bid = blockIdx.x;          // ((b*V+v)*HH + h)*P + qi
    int qi = bid % P, h = (bid / P) % HH, v = (bid / (P * HH)) % V, b = bid / (P * HH * V);
    int j = threadIdx.x;
    __shared__ float attn[256];
    __shared__ float red[256];
    float flag = ws[MFLAG + b * V + v];
    float val = -1e30f;
    if (j < P) {
        float lg = ws[LOGo + ((size_t)(b * HH + h) * P + qi) * P + j];
        bool mk = (flag > 0.5f) && (maskin[(b * P + j) * V + v] > 0);
        val = lg + (mk ? 0.f : -1e9f);
    }
    float mx = blockReduceMax(val, red);
    float e = (j < P) ? __expf(val - mx) : 0.f;
    float s = blockReduceSum(e, red);
    attn[j] = e / s;
    __syncthreads();
    int d = j & 31, c = j >> 5;
    const float* vvp = ws + VVo + (size_t)b * P * C + h * Dh + d;
    float acc = 0.f;
    for (int kk = c * 25; kk < c * 25 + 25; ++kk) acc += attn[kk] * vvp[(size_t)kk * C];
    red[j] = acc; __syncthreads();
    if (j < Dh) {
        float s2 = 0.f;
        for (int c2 = 0; c2 < 8; c2++) s2 += red[c2 * 32 + j];
        ws[SAo + ((size_t)((b * V + v) * P + qi)) * C + h * Dh + j] = s2;
    }
}

// ---------------- sa @ wo + residual + LN -> x1 ----------------
__global__ __launch_bounds__(256) void k_saout(const float* wo, float* ws) {
    int row = blockIdx.x, j = threadIdx.x;
    int p = row % P, b = row / (P * V);
    __shared__ __align__(16) float in[C];
    __shared__ float red[256];
    in[j] = ws[SAo + (size_t)row * C + j];
    __syncthreads();
    float t = dotK(in, wo, j, C, C);
    float r = ws[Xo + ((size_t)(b * P + p)) * C + j] + t;
    float mean = blockReduceSum(r, red) * (1.f / C);
    float diff = r - mean;
    float var = blockReduceSum(diff * diff, red) * (1.f / C);
    ws[X1o + (size_t)row * C + j] = diff * rsqrtf(var + 1e-5f);
}

// ---------------- reference points ----------------
__global__ __launch_bounds__(256) void k_ref(const float* qposin, const float* rt, float* ws) {
    int tid = blockIdx.x * 256 + threadIdx.x;
    if (tid >= BVP) return;
    int p = tid % P, v = (tid / P) % V, b = tid / (P * V);
    float p0 = qposin[(b * P + p) * 3 + 0];
    float p1 = qposin[(b * P + p) * 3 + 1];
    float p2 = qposin[(b * P + p) * 3 + 2];
    const float* m = rt + (size_t)(b * V + v) * 16;
    float pr[3];
    for (int i = 0; i < 3; i++)
        pr[i] = m[i * 4 + 0] * p0 + m[i * 4 + 1] * p1 + m[i * 4 + 2] * p2 + m[i * 4 + 3];
    ws[REFo + (size_t)tid * 2 + 0] = pr[0] / pr[2] / IMG_W;
    ws[REFo + (size_t)tid * 2 + 1] = pr[1] / pr[2] / IMG_H;
}

// ---------------- offsets + attention weights heads ----------------
__global__ __launch_bounds__(256) void k_offaw(const float* ow, const float* ob, const float* aw_w, const float* aw_b,
                                               float* ws) {
    int row = blockIdx.x, j = threadIdx.x;
    int p = row % P, b = row / (P * V);
    __shared__ __align__(16) float q2[C];
    __shared__ float al[128];
    q2[j] = ws[X1o + (size_t)row * C + j] + ws[QPOSo + ((size_t)(b * P + p)) * C + j];
    __syncthreads();
    float offv = ob[j] + dotK(q2, ow, j, 256, C);
    ws[OFFo + (size_t)row * 256 + j] = offv;
    if (j < 128) al[j] = aw_b[j] + dotK(q2, aw_w, j, 128, C);
    __syncthreads();
    if (j < 128) {
        int g = (j >> 4) << 4;
        float mx = -1e30f;
        for (int i = 0; i < 16; i++) mx = fmaxf(mx, al[g + i]);
        float s = 0.f;
        for (int i = 0; i < 16; i++) s += __expf(al[g + i] - mx);
        ws[AWo + (size_t)row * 128 + j] = __expf(al[j] - mx) / s;
    }
}

// ---------------- vals via MFMA: vals = (relu(kp6@kw1+b1)@kw2 + b2 + feat) @ dvw ----------------
constexpr int ASTR = C + 8;   // 264 bf16 -> row stride 528 B = 33*16B (aligned b128, conflict-light)
constexpr int NLT = (L + 127) / 128;   // 59

__global__ __launch_bounds__(256, 2) void k_vals_mfma(
        const float* __restrict__ npos, const float* __restrict__ feats,
        const float* __restrict__ kw1, const float* __restrict__ kb1, const float* __restrict__ kb2,
        const bf16* __restrict__ kw2T, const bf16* __restrict__ dvwT,
        const float* __restrict__ ws, bf16* __restrict__ vals) {
    __shared__ __align__(16) bf16 As[128 * ASTR];
    __shared__ float kp6s[128][8];
    int bv = blockIdx.y;
    int l0 = blockIdx.x * 128;
    int t = threadIdx.x;
    // phase 0: per-row 6-dim key_pos
    if (t < 128) {
        int l = min(l0 + t, L - 1);
        float sx = 1.f / (1.f + __expf(-npos[l * 2 + 0])) * IMG_W;
        float sy = 1.f / (1.f + __expf(-npos[l * 2 + 1])) * IMG_H;
        const float* inv = ws + IRT + (size_t)bv * 16;
        #pragma unroll
        for (int i = 0; i < 3; i++)
            kp6s[t][i] = inv[i * 4 + 0] * sx + inv[i * 4 + 1] * sy + inv[i * 4 + 2] + inv[i * 4 + 3];
        #pragma unroll
        for (int i = 0; i < 3; i++) kp6s[t][3 + i] = ws[CAMT + (size_t)bv * 3 + i];
    }
    __syncthreads();
    // phase 1: hid = relu(kp6 @ kw1 + kb1) -> As (bf16)
    {
        float w1j[6];
        #pragma unroll
        for (int k2 = 0; k2 < 6; k2++) w1j[k2] = kw1[k2 * C + t];
        float bb = kb1[t];
        for (int r = 0; r < 128; r++) {
            float h = bb;
            #pragma unroll
            for (int k2 = 0; k2 < 6; k2++) h += kp6s[r][k2] * w1j[k2];
            As[r * ASTR + t] = tobf(fmaxf(h, 0.f));
        }
    }
    __syncthreads();
    int wave = t >> 6, lane = t & 63;
    int quad = lane >> 4, l15 = lane & 15;
    int mbase = wave * 32;              // this wave owns rows [mbase, mbase+32)
    floatx4 acc[2][16];
    // ---- GEMM1: vin = hid @ kw2 ----
    #pragma unroll
    for (int i = 0; i < 2; i++)
        #pragma unroll
        for (int nt = 0; nt < 16; nt++) acc[i][nt] = (floatx4){0.f, 0.f, 0.f, 0.f};
    for (int kk = 0; kk < 8; kk++) {
        short8 a0 = *(const short8*)&As[(mbase + l15) * ASTR + kk * 32 + quad * 8];
        short8 a1 = *(const short8*)&As[(mbase + 16 + l15) * ASTR + kk * 32 + quad * 8];
        #pragma unroll
        for (int nt = 0; nt < 16; nt++) {
            short8 bfr = *(const short8*)&kw2T[(size_t)(nt * 16 + l15) * C + kk * 32 + quad * 8];
            acc[0][nt] = __builtin_amdgcn_mfma_f32_16x16x32_bf16(a0, bfr, acc[0][nt], 0, 0, 0);
            acc[1][nt] = __builtin_amdgcn_mfma_f32_16x16x32_bf16(a1, bfr, acc[1][nt], 0, 0, 0);
        }
    }
    // epilogue 1: vin = acc + kb2 + feat -> back into As (wave-private rows, no barrier)
    #pragma unroll
    for (int i = 0; i < 2; i++) {
        #pragma unroll
        for (int nt = 0; nt < 16; nt++) {
            int c = nt * 16 + l15;
            int rloc = mbase + i * 16 + quad * 4;
            float bias = kb2[c];
            const float* fp = feats + ((size_t)bv * C + c) * L + l0 + rloc;
            #pragma unroll
            for (int u = 0; u < 4; u++) {
                float fv = (l0 + rloc + u < L) ? fp[u] : 0.f;
                As[(rloc + u) * ASTR + c] = tobf(acc[i][nt][u] + bias + fv);
            }
        }
    }
    // ---- GEMM2: vals = vin @ dvw ----
    #pragma unroll
    for (int i = 0; i < 2; i++)
        #pragma unroll
        for (int nt = 0; nt < 16; nt++) acc[i][nt] = (floatx4){0.f, 0.f, 0.f, 0.f};
    for (int kk = 0; kk < 8; kk++) {
        short8 a0 = *(const short8*)&As[(mbase + l15) * ASTR + kk * 32 + quad * 8];
        short8 a1 = *(const short8*)&As[(mbase + 16 + l15) * ASTR + kk * 32 + quad * 8];
        #pragma unroll
        for (int nt = 0; nt < 16; nt++) {
            short8 bfr = *(const short8*)&dvwT[(size_t)(nt * 16 + l15) * C + kk * 32 + quad * 8];
            acc[0][nt] = __builtin_amdgcn_mfma_f32_16x16x32_bf16(a0, bfr, acc[0][nt], 0, 0, 0);
            acc[1][nt] = __builtin_amdgcn_mfma_f32_16x16x32_bf16(a1, bfr, acc[1][nt], 0, 0, 0);
        }
    }
    // epilogue 2: store bf16 vals
    #pragma unroll
    for (int i = 0; i < 2; i++) {
        #pragma unroll
        for (int nt = 0; nt < 16; nt++) {
            int c = nt * 16 + l15;
            int rloc = mbase + i * 16 + quad * 4;
            #pragma unroll
            for (int u = 0; u < 4; u++) {
                int l = l0 + rloc + u;
                if (l < L) vals[((size_t)bv * L + l) * C + c] = tobf(acc[i][nt][u]);
            }
        }
    }
}

// ---------------- deformable bilinear sampling + weighted sum ----------------
__global__ __launch_bounds__(256) void k_sample(const float* ws, const bf16* vals, float* wsmut) {
    int row = blockIdx.x, j = threadIdx.x;
    int h = j >> 5, d = j & 31;
    __shared__ float soff[256];
    __shared__ float sawL[128];
    __shared__ float sref[2];
    soff[j] = ws[OFFo + (size_t)row * 256 + j];
    if (j < 128) sawL[j] = ws[AWo + (size_t)row * 128 + j];
    if (j < 2) sref[j] = ws[REFo + (size_t)row * 2 + j];
    __syncthreads();
    int v = (row / P) % V, b = row / (P * V);
    const bf16* vbase = vals + (size_t)(b * V + v) * L * C + h * Dh + d;
    float acc = 0.f;
    for (int l = 0; l < NLEV; l++) {
        float Wf = (float)cLW[l], Hf = (float)cLH[l];
        int Wi = cLW[l], Hi = cLH[l], S0 = cLS[l];
        for (int n = 0; n < NPTS; n++) {
            int oi = ((h * NLEV + l) * NPTS + n) * 2;
            float lx = sref[0] + soff[oi + 0] / Wf;
            float ly = sref[1] + soff[oi + 1] / Hf;
            float aww = sawL[(h * NLEV + l) * NPTS + n];
            float x = lx * Wf - 0.5f, y = ly * Hf - 0.5f;
            float x0f = floorf(x), y0f = floorf(y);
            float wx = x - x0f, wy = y - y0f;
            int x0 = (int)x0f, y0 = (int)y0f;
            float s = 0.f;
            #pragma unroll
            for (int dy = 0; dy < 2; dy++) {
                #pragma unroll
                for (int dx = 0; dx < 2; dx++) {
                    int xi = x0 + dx, yi = y0 + dy;
                    if (xi >= 0 && xi < Wi && yi >= 0 && yi < Hi) {
                        float wwt = (dx ? wx : 1.f - wx) * (dy ? wy : 1.f - wy);
                        s += wwt * tof(vbase[(size_t)(S0 + yi * Wi + xi) * C]);
                    }
                }
            }
            acc += aww * s;
        }
    }
    wsmut[OUTSo + (size_t)row * C + j] = acc;
}

// ---------------- out @ dout_w + x1 + LN -> x2 ----------------
__global__ __launch_bounds__(256) void k_dout(const float* dw, float* ws) {
    int row = blockIdx.x, j = threadIdx.x;
    __shared__ __align__(16) float in[C];
    __shared__ float red[256];
    in[j] = ws[OUTSo + (size_t)row * C + j];
    __syncthreads();
    float t = dotK(in, dw, j, C, C);
    float r = ws[X1o + (size_t)row * C + j] + t;
    float mean = blockReduceSum(r, red) * (1.f / C);
    float diff = r - mean;
    float var = blockReduceSum(diff * diff, red) * (1.f / C);
    ws[X2o + (size_t)row * C + j] = diff * rsqrtf(var + 1e-5f);
}

// ---------------- FFN + LN -> x3 ----------------
__global__ __launch_bounds__(256) void k_ffn(const float* w1, const float* b1, const float* w2, const float* b2,
                                             float* ws) {
    int row = blockIdx.x, j = threadIdx.x;
    __shared__ __align__(16) float in[C];
    __shared__ __align__(16) float hid[FFN];
    __shared__ float red[256];
    float xv = ws[X2o + (size_t)row * C + j];
    in[j] = xv;
    __syncthreads();
    for (int u = 0; u < 4; u++) {
        int jj = j + u * 256;
        float acc = b1[jj];
        for (int k = 0; k < C; k += 4) {
            float4 h = *(const float4*)&in[k];
            acc += h.x * w1[(size_t)(k + 0) * FFN + jj];
            acc += h.y * w1[(size_t)(k + 1) * FFN + jj];
            acc += h.z * w1[(size_t)(k + 2) * FFN + jj];
            acc += h.w * w1[(size_t)(k + 3) * FFN + jj];
        }
        hid[jj] = fmaxf(acc, 0.f);
    }
    __syncthreads();
    float acc = b2[j] + dotK(hid, w2, j, C, FFN);
    float r = xv + acc;
    float mean = blockReduceSum(r, red) * (1.f / C);
    float diff = r - mean;
    float var = blockReduceSum(diff * diff, red) * (1.f / C);
    ws[X3o + (size_t)row * C + j] = diff * rsqrtf(var + 1e-5f);
}

// ---------------- masked view-mean + output0 ----------------
__global__ __launch_bounds__(256) void k_fuse(const int* maskin, float* ws, float* out) {
    int row = blockIdx.x, j = threadIdx.x;
    int b = row / P, p = row % P;
    float s = 0.f, cnt = 0.f;
    for (int v = 0; v < V; v++) {
        bool mk = (maskin[(b * P + p) * V + v] > 0) && (ws[MFLAG + b * V + v] > 0.5f);
        if (mk) {
            s += ws[X3o + ((size_t)((b * V + v) * P + p)) * C + j];
            cnt += 1.f;
        }
    }
    float f = s / (cnt + 1e-4f);
    ws[FUSEDo + (size_t)row * C + j] = f;
    out[O0 + ((size_t)b * C + j) * P + p] = f;
}

// ---------------- pred head + BEV outputs ----------------
__global__ __launch_bounds__(256) void k_pred(const float* w1, const float* b1, const float* w2, const float* b2,
                                              const float* qposin, float* ws, float* out) {
    int row = blockIdx.x, j = threadIdx.x;
    __shared__ __align__(16) float in[C];
    __shared__ float red[256];
    __shared__ float cen[4];
    in[j] = ws[FUSEDo + (size_t)row * C + j];
    __syncthreads();
    float h = fmaxf(b1[j] + dotK(in, w1, j, C, C), 0.f);
    for (int i = 0; i < 3; i++) {
        float s = blockReduceSum(h * w2[j * 3 + i], red);
        if (j == 0) cen[i] = s + b2[i] + qposin[row * 3 + i];
    }
    if (j == 0) {
        float c0 = cen[0], c1 = cen[1], c2 = cen[2];
        float cx = (c0 + 54.f) / 108.f * 135.f;
        float cy = (c1 + 54.f) / 108.f * 135.f;
        int b = row / P, p = row % P;
        out[O1 + (size_t)row * 3 + 0] = c0;
        out[O1 + (size_t)row * 3 + 1] = c1;
        out[O1 + (size_t)row * 3 + 2] = c2;
        out[O2 + (size_t)row * 2 + 0] = cx;
        out[O2 + (size_t)row * 2 + 1] = cy;
        out[O3 + (size_t)b * 2 * P + 0 * P + p] = cx;
        out[O3 + (size_t)b * 2 * P + 1 * P + p] = cy;
        out[O4 + (size_t)b * P + p] = c2;
    }
}

extern "C" void kernel_launch(void* const* d_in, const int* in_sizes, int n_in,
                              void* d_out, int out_size, void* d_ws, size_t ws_size,
                              hipStream_t stream) {
    const float* qfeat  = (const float*)d_in[0];
    const float* qposin = (const float*)d_in[1];
    const int*   maskin = (const int*)d_in[2];
    const float* feats  = (const float*)d_in[3];
    const float* npos   = (const float*)d_in[4];
    const float* rt     = (const float*)d_in[5];
    const float* l2cr   = (const float*)d_in[6];
    const float* l2ct   = (const float*)d_in[7];
    const float* qp_w1 = (const float*)d_in[8],  * qp_b1 = (const float*)d_in[9];
    const float* qp_w2 = (const float*)d_in[10], * qp_b2 = (const float*)d_in[11];
    const float* kp_w1 = (const float*)d_in[12], * kp_b1 = (const float*)d_in[13];
    const float* kp_w2 = (const float*)d_in[14], * kp_b2 = (const float*)d_in[15];
    const float* sa_wq = (const float*)d_in[16], * sa_wk = (const float*)d_in[17];
    const float* sa_wv = (const float*)d_in[18], * sa_wo = (const float*)d_in[19];
    const float* dv_w  = (const float*)d_in[20];
    const float* doffw = (const float*)d_in[21], * doffb = (const float*)d_in[22];
    const float* dattw = (const float*)d_in[23], * dattb = (const float*)d_in[24];
    const float* doutw = (const float*)d_in[25];
    const float* f_w1  = (const float*)d_in[26], * f_b1 = (const float*)d_in[27];
    const float* f_w2  = (const float*)d_in[28], * f_b2 = (const float*)d_in[29];
    const float* p_w1  = (const float*)d_in[30], * p_b1 = (const float*)d_in[31];
    const float* p_w2  = (const float*)d_in[32], * p_b2 = (const float*)d_in[33];

    float* ws = (float*)d_ws;
    bf16* vals = (bf16*)((char*)d_ws + VALS_BYTE_OFF);
    bf16* kw2T = vals + VALS_ELEMS;
    bf16* dvwT = kw2T + (size_t)C * C;
    float* out = (float*)d_out;

    k_setup<<<1, 64, 0, stream>>>(rt, l2cr, l2ct, maskin, ws);
    k_wprep<<<512, 256, 0, stream>>>(kp_w2, dv_w, kw2T, dvwT);
    k_qpos<<<BP, 256, 0, stream>>>(qfeat, qposin, qp_w1, qp_b1, qp_w2, qp_b2, ws);
    k_qkv<<<dim3(BP, 3), 256, 0, stream>>>(sa_wq, sa_wk, sa_wv, ws);
    k_logits<<<B * HH * P, 256, 0, stream>>>(ws);
    k_sattn<<<B * V * HH * P, 256, 0, stream>>>(maskin, ws);
    k_saout<<<BVP, 256, 0, stream>>>(sa_wo, ws);
    k_ref<<<(BVP + 255) / 256, 256, 0, stream>>>(qposin, rt, ws);
    k_offaw<<<BVP, 256, 0, stream>>>(doffw, doffb, dattw, dattb, ws);
    k_vals_mfma<<<dim3(NLT, BV), 256, 0, stream>>>(npos, feats, kp_w1, kp_b1, kp_b2, kw2T, dvwT, ws, vals);
    k_sample<<<BVP, 256, 0, stream>>>(ws, vals, ws);
    k_dout<<<BVP, 256, 0, stream>>>(doutw, ws);
    k_ffn<<<BVP, 256, 0, stream>>>(f_w1, f_b1, f_w2, f_b2, ws);
    k_fuse<<<BP, 256, 0, stream>>>(maskin, ws, out);
    k_pred<<<BP, 256, 0, stream>>>(p_w1, p_b1, p_w2, p_b2, qposin, ws, out);
}

// Round 4
// 1180.146 us; speedup vs baseline: 1.6876x; 1.1663x over previous
//
#include <hip/hip_runtime.h>
#include <hip/hip_bf16.h>
#include <cstdint>
#include <cstddef>

using bf16 = __hip_bfloat16;
#define DEVFN static __device__ __forceinline__

constexpr int B = 4, V = 6, P = 200, C = 256, HH = 8, Dh = 32, NLEV = 4, NPTS = 4, FFN = 1024;
constexpr int L = 7441;
constexpr int BV = B * V, BP = B * P, BVP = B * V * P, BVL = B * V * L;
constexpr float IMG_W = 800.f, IMG_H = 448.f;

__constant__ int cLH[4] = {56, 28, 14, 7};
__constant__ int cLW[4] = {100, 50, 25, 13};
__constant__ int cLS[4] = {0, 5600, 7000, 7350};

// ---- workspace layout (offsets in floats) ----
constexpr size_t IRT   = 0;
constexpr size_t CAMT  = IRT + (size_t)BV * 16;
constexpr size_t MFLAG = CAMT + (size_t)BV * 3;
constexpr size_t Xo    = MFLAG + BV;
constexpr size_t QPOSo = Xo + (size_t)BP * C;
constexpr size_t Qo    = QPOSo + (size_t)BP * C;
constexpr size_t Ko    = Qo + (size_t)BP * C;
constexpr size_t VVo   = Ko + (size_t)BP * C;
constexpr size_t LOGo  = VVo + (size_t)BP * C;
constexpr size_t SAo   = LOGo + (size_t)B * HH * P * P;
constexpr size_t X1o   = SAo + (size_t)BVP * C;
constexpr size_t REFo  = X1o + (size_t)BVP * C;
constexpr size_t OFFo  = REFo + (size_t)BVP * 2;
constexpr size_t AWo   = OFFo + (size_t)BVP * 256;
constexpr size_t OUTSo = AWo + (size_t)BVP * 128;
constexpr size_t X2o   = OUTSo + (size_t)BVP * C;
constexpr size_t X3o   = X2o + (size_t)BVP * C;
constexpr size_t FUSEDo= X3o + (size_t)BVP * C;
constexpr size_t WS_FLOATS = FUSEDo + (size_t)BP * C;
constexpr size_t VALS_BYTE_OFF = ((WS_FLOATS * 4 + 255) / 256) * 256;
constexpr size_t VALS_ELEMS = (size_t)BVL * C;   // bf16

// ---- output layout (elements, f32) ----
constexpr size_t O0 = 0;                          // (B,C,P)
constexpr size_t O1 = O0 + (size_t)B * C * P;     // (B,P,3)
constexpr size_t O2 = O1 + (size_t)B * P * 3;     // (B,P,2)
constexpr size_t O3 = O2 + (size_t)B * P * 2;     // (B,2,P)
constexpr size_t O4 = O3 + (size_t)B * 2 * P;     // (B,1,P)

DEVFN float tof(bf16 x) { return __bfloat162float(x); }
DEVFN bf16  tobf(float x) { return __float2bfloat16(x); }

typedef __attribute__((ext_vector_type(8))) short short8;
typedef __attribute__((ext_vector_type(4))) float floatx4;

DEVFN float blockReduceSum(float v, float* red) {
    int j = threadIdx.x;
    __syncthreads();
    red[j] = v; __syncthreads();
    for (int s = 128; s > 0; s >>= 1) { if (j < s) red[j] += red[j + s]; __syncthreads(); }
    return red[0];
}
DEVFN float blockReduceMax(float v, float* red) {
    int j = threadIdx.x;
    __syncthreads();
    red[j] = v; __syncthreads();
    for (int s = 128; s > 0; s >>= 1) { if (j < s) red[j] = fmaxf(red[j], red[j + s]); __syncthreads(); }
    return red[0];
}

// out_j = sum_k s[k] * W[k*N + j]   (W f32 row-major (K,N), s in LDS)
DEVFN float dotK(const float* __restrict__ s, const float* __restrict__ W, int j, int N, int K) {
    float acc = 0.f;
    for (int k = 0; k < K; k += 4) {
        float4 h = *(const float4*)(s + k);
        acc += h.x * W[(size_t)(k + 0) * N + j];
        acc += h.y * W[(size_t)(k + 1) * N + j];
        acc += h.z * W[(size_t)(k + 2) * N + j];
        acc += h.w * W[(size_t)(k + 3) * N + j];
    }
    return acc;
}

// ---------------- setup: inverse(rt), cam_t, view-valid flag ----------------
__global__ __launch_bounds__(64) void k_setup(const float* rt, const float* l2cr, const float* l2ct,
                                              const int* maskin, float* ws) {
    int t = threadIdx.x;
    if (t >= BV) return;
    float m[16], inv[16];
    for (int i = 0; i < 16; i++) m[i] = rt[t * 16 + i];
    inv[0]  =  m[5]*m[10]*m[15] - m[5]*m[11]*m[14] - m[9]*m[6]*m[15] + m[9]*m[7]*m[14] + m[13]*m[6]*m[11] - m[13]*m[7]*m[10];
    inv[4]  = -m[4]*m[10]*m[15] + m[4]*m[11]*m[14] + m[8]*m[6]*m[15] - m[8]*m[7]*m[14] - m[12]*m[6]*m[11] + m[12]*m[7]*m[10];
    inv[8]  =  m[4]*m[9]*m[15]  - m[4]*m[11]*m[13] - m[8]*m[5]*m[15] + m[8]*m[7]*m[13] + m[12]*m[5]*m[11] - m[12]*m[7]*m[9];
    inv[12] = -m[4]*m[9]*m[14]  + m[4]*m[10]*m[13] + m[8]*m[5]*m[14] - m[8]*m[6]*m[13] - m[12]*m[5]*m[10] + m[12]*m[6]*m[9];
    inv[1]  = -m[1]*m[10]*m[15] + m[1]*m[11]*m[14] + m[9]*m[2]*m[15] - m[9]*m[3]*m[14] - m[13]*m[2]*m[11] + m[13]*m[3]*m[10];
    inv[5]  =  m[0]*m[10]*m[15] - m[0]*m[11]*m[14] - m[8]*m[2]*m[15] + m[8]*m[3]*m[14] + m[12]*m[2]*m[11] - m[12]*m[3]*m[10];
    inv[9]  = -m[0]*m[9]*m[15]  + m[0]*m[11]*m[13] + m[8]*m[1]*m[15] - m[8]*m[3]*m[13] - m[12]*m[1]*m[11] + m[12]*m[3]*m[9];
    inv[13] =  m[0]*m[9]*m[14]  - m[0]*m[10]*m[13] - m[8]*m[1]*m[14] + m[8]*m[2]*m[13] + m[12]*m[1]*m[10] - m[12]*m[2]*m[9];
    inv[2]  =  m[1]*m[6]*m[15]  - m[1]*m[7]*m[14]  - m[5]*m[2]*m[15] + m[5]*m[3]*m[14] + m[13]*m[2]*m[7]  - m[13]*m[3]*m[6];
    inv[6]  = -m[0]*m[6]*m[15]  + m[0]*m[7]*m[14]  + m[4]*m[2]*m[15] - m[4]*m[3]*m[14] - m[12]*m[2]*m[7]  + m[12]*m[3]*m[6];
    inv[10] =  m[0]*m[5]*m[15]  - m[0]*m[7]*m[13]  - m[4]*m[1]*m[15] + m[4]*m[3]*m[13] + m[12]*m[1]*m[7]  - m[12]*m[3]*m[5];
    inv[14] = -m[0]*m[5]*m[14]  + m[0]*m[6]*m[13]  + m[4]*m[1]*m[14] - m[4]*m[2]*m[13] - m[12]*m[1]*m[6]  + m[12]*m[2]*m[5];
    inv[3]  = -m[1]*m[6]*m[11]  + m[1]*m[7]*m[10]  + m[5]*m[2]*m[11] - m[5]*m[3]*m[10] - m[9]*m[2]*m[7]   + m[9]*m[3]*m[6];
    inv[7]  =  m[0]*m[6]*m[11]  - m[0]*m[7]*m[10]  - m[4]*m[2]*m[11] + m[4]*m[3]*m[10] + m[8]*m[2]*m[7]   - m[8]*m[3]*m[6];
    inv[11] = -m[0]*m[5]*m[11]  + m[0]*m[7]*m[9]   + m[4]*m[1]*m[11] - m[4]*m[3]*m[9]  - m[8]*m[1]*m[7]   + m[8]*m[3]*m[5];
    inv[15] =  m[0]*m[5]*m[10]  - m[0]*m[6]*m[9]   - m[4]*m[1]*m[10] + m[4]*m[2]*m[9]  + m[8]*m[1]*m[6]   - m[8]*m[2]*m[5];
    float det = m[0]*inv[0] + m[1]*inv[4] + m[2]*inv[8] + m[3]*inv[12];
    float rd = 1.f / det;
    for (int i = 0; i < 16; i++) ws[IRT + t * 16 + i] = inv[i] * rd;
    float r9[9], tv[3];
    for (int i = 0; i < 9; i++) r9[i] = l2cr[t * 9 + i];
    for (int i = 0; i < 3; i++) tv[i] = l2ct[t * 3 + i];
    for (int i = 0; i < 3; i++)
        ws[CAMT + t * 3 + i] = -(r9[0 * 3 + i] * tv[0] + r9[1 * 3 + i] * tv[1] + r9[2 * 3 + i] * tv[2]);
    int b = t / V, v = t % V, cnt = 0;
    for (int p = 0; p < P; p++) cnt += (maskin[(b * P + p) * V + v] > 0) ? 1 : 0;
    ws[MFLAG + t] = (cnt > 1) ? 1.f : 0.f;
}

// ---------------- weight prep: transpose + bf16 cast for MFMA B operands ----------------
__global__ __launch_bounds__(256) void k_wprep(const float* kw2, const float* dvw, bf16* kw2T, bf16* dvwT) {
    int n = blockIdx.x & 255;
    int k = threadIdx.x;
    if (blockIdx.x < 256) kw2T[n * 256 + k] = tobf(kw2[(size_t)k * 256 + n]);
    else                  dvwT[n * 256 + k] = tobf(dvw[(size_t)k * 256 + n]);
}

// ---------------- qpos MLP + x transpose ----------------
__global__ __launch_bounds__(256) void k_qpos(const float* qfeat, const float* qposin,
                                              const float* w1, const float* b1, const float* w2, const float* b2,
                                              float* ws) {
    int row = blockIdx.x, j = threadIdx.x;
    int b = row / P, p = row % P;
    __shared__ __align__(16) float pos[4];
    __shared__ __align__(16) float hid[C];
    if (j < 3) pos[j] = qposin[row * 3 + j];
    __syncthreads();
    float h = b1[j] + pos[0] * w1[0 * C + j] + pos[1] * w1[1 * C + j] + pos[2] * w1[2 * C + j];
    hid[j] = fmaxf(h, 0.f);
    __syncthreads();
    float acc = b2[j] + dotK(hid, w2, j, C, C);
    ws[QPOSo + (size_t)row * C + j] = acc;
    ws[Xo + (size_t)row * C + j] = qfeat[((size_t)b * C + j) * P + p];
}

// ---------------- q / k / v projections ----------------
__global__ __launch_bounds__(256) void k_qkv(const float* wq, const float* wk, const float* wv, float* ws) {
    int row = blockIdx.x, which = blockIdx.y, j = threadIdx.x;
    __shared__ __align__(16) float in[C];
    float xv = ws[Xo + (size_t)row * C + j];
    in[j] = (which < 2) ? (xv + ws[QPOSo + (size_t)row * C + j]) : xv;
    __syncthreads();
    const float* W = (which == 0) ? wq : (which == 1) ? wk : wv;
    float acc = dotK(in, W, j, C, C);
    size_t dst = (which == 0) ? Qo : (which == 1) ? Ko : VVo;
    ws[dst + (size_t)row * C + j] = acc;
}

// ---------------- attention logits ----------------
__global__ __launch_bounds__(256) void k_logits(float* ws) {
    int bid = blockIdx.x;          // (b*HH + h)*P + qi
    int qi = bid % P, h = (bid / P) % HH, b = bid / (P * HH);
    int j = threadIdx.x;
    __shared__ __align__(16) float qf[Dh];
    if (j < Dh) qf[j] = ws[Qo + ((size_t)(b * P + qi)) * C + h * Dh + j];
    __syncthreads();
    if (j < P) {
        const float* kp = ws + Ko + ((size_t)(b * P + j)) * C + h * Dh;
        float acc = 0.f;
        for (int d = 0; d < Dh; d += 4) {
            float4 kv = *(const float4*)(kp + d);
            float4 qv = *(const float4*)(qf + d);
            acc += kv.x * qv.x + kv.y * qv.y + kv.z * qv.z + kv.w * qv.w;
        }
        ws[LOGo + (size_t)bid * P + j] = acc * 0.17677669529663687f;
    }
}

// ---------------- masked softmax + attn @ V ----------------
__global__ __launch_bounds__(256) void k_sattn(const int* maskin, float* ws) {
    int bid = blockIdx.x;          // ((b*V+v)*HH + h)*P + qi
    int qi = bid % P, h = (bid / P) % HH, v = (bid / (P * HH)) % V, b = bid / (P * HH * V);
    int j = threadIdx.x;
    __shared__ float attn[256];
    __shared__ float red[256];
    float flag = ws[MFLAG + b * V + v];
    float val = -1e30f;
    if (j < P) {
        float lg = ws[LOGo + ((size_t)(b * HH + h) * P + qi) * P + j];
        bool mk = (flag > 0.5f) && (maskin[(b * P + j) * V + v] > 0);
        val = lg + (mk ? 0.f : -1e9f);
    }
    float mx = blockReduceMax(val, red);
    float e = (j < P) ? __expf(val - mx) : 0.f;
    float s = blockReduceSum(e, red);
    attn[j] = e / s;
    __syncthreads();
    int d = j & 31, c = j >> 5;
    const float* vvp = ws + VVo + (size_t)b * P * C + h * Dh + d;
    float acc = 0.f;
    for (int kk = c * 25; kk < c * 25 + 25; ++kk) acc += attn[kk] * vvp[(size_t)kk * C];
    red[j] = acc; __syncthreads();
    if (j < Dh) {
        float s2 = 0.f;
        for (int c2 = 0; c2 < 8; c2++) s2 += red[c2 * 32 + j];
        ws[SAo + ((size_t)((b * V + v) * P + qi)) * C + h * Dh + j] = s2;
    }
}

// ---------------- sa @ wo + residual + LN -> x1 ----------------
__global__ __launch_bounds__(256) void k_saout(const float* wo, float* ws) {
    int row = blockIdx.x, j = threadIdx.x;
    int p = row % P, b = row / (P * V);
    __shared__ __align__(16) float in[C];
    __shared__ float red[256];
    in[j] = ws[SAo + (size_t)row * C + j];
    __syncthreads();
    float t = dotK(in, wo, j, C, C);
    float r = ws[Xo + ((size_t)(b * P + p)) * C + j] + t;
    float mean = blockReduceSum(r, red) * (1.f / C);
    float diff = r - mean;
    float var = blockReduceSum(diff * diff, red) * (1.f / C);
    ws[X1o + (size_t)row * C + j] = diff * rsqrtf(var + 1e-5f);
}

// ---------------- reference points ----------------
__global__ __launch_bounds__(256) void k_ref(const float* qposin, const float* rt, float* ws) {
    int tid = blockIdx.x * 256 + threadIdx.x;
    if (tid >= BVP) return;
    int p = tid % P, v = (tid / P) % V, b = tid / (P * V);
    float p0 = qposin[(b * P + p) * 3 + 0];
    float p1 = qposin[(b * P + p) * 3 + 1];
    float p2 = qposin[(b * P + p) * 3 + 2];
    const float* m = rt + (size_t)(b * V + v) * 16;
    float pr[3];
    for (int i = 0; i < 3; i++)
        pr[i] = m[i * 4 + 0] * p0 + m[i * 4 + 1] * p1 + m[i * 4 + 2] * p2 + m[i * 4 + 3];
    ws[REFo + (size_t)tid * 2 + 0] = pr[0] / pr[2] / IMG_W;
    ws[REFo + (size_t)tid * 2 + 1] = pr[1] / pr[2] / IMG_H;
}

// ---------------- offsets + attention weights heads ----------------
__global__ __launch_bounds__(256) void k_offaw(const float* ow, const float* ob, const float* aw_w, const float* aw_b,
                                               float* ws) {
    int row = blockIdx.x, j = threadIdx.x;
    int p = row % P, b = row / (P * V);
    __shared__ __align__(16) float q2[C];
    __shared__ float al[128];
    q2[j] = ws[X1o + (size_t)row * C + j] + ws[QPOSo + ((size_t)(b * P + p)) * C + j];
    __syncthreads();
    float offv = ob[j] + dotK(q2, ow, j, 256, C);
    ws[OFFo + (size_t)row * 256 + j] = offv;
    if (j < 128) al[j] = aw_b[j] + dotK(q2, aw_w, j, 128, C);
    __syncthreads();
    if (j < 128) {
        int g = (j >> 4) << 4;
        float mx = -1e30f;
        for (int i = 0; i < 16; i++) mx = fmaxf(mx, al[g + i]);
        float s = 0.f;
        for (int i = 0; i < 16; i++) s += __expf(al[g + i] - mx);
        ws[AWo + (size_t)row * 128 + j] = __expf(al[j] - mx) / s;
    }
}

// ---------------- vals via MFMA (64-row tiles, prefetched feats, coalesced store) ----------------
constexpr int VROWS = 64;
constexpr int ASTR = C + 8;                     // 264 elems -> 528 B row stride (33*16B)
constexpr int NVT = (L + VROWS - 1) / VROWS;    // 117

__global__ __launch_bounds__(256, 2) void k_vals_mfma(
        const float* __restrict__ npos, const float* __restrict__ feats,
        const float* __restrict__ kw1, const float* __restrict__ kb1, const float* __restrict__ kb2,
        const bf16* __restrict__ kw2T, const bf16* __restrict__ dvwT,
        const float* __restrict__ ws, bf16* __restrict__ vals) {
    __shared__ __align__(16) bf16 As[VROWS * ASTR];
    __shared__ float kp6s[VROWS][8];
    int bv = blockIdx.y;
    int l0 = blockIdx.x * VROWS;
    int t = threadIdx.x;
    // phase 0: per-row 6-dim key_pos
    if (t < VROWS) {
        int l = min(l0 + t, L - 1);
        float sx = 1.f / (1.f + __expf(-npos[l * 2 + 0])) * IMG_W;
        float sy = 1.f / (1.f + __expf(-npos[l * 2 + 1])) * IMG_H;
        const float* inv = ws + IRT + (size_t)bv * 16;
        #pragma unroll
        for (int i = 0; i < 3; i++)
            kp6s[t][i] = inv[i * 4 + 0] * sx + inv[i * 4 + 1] * sy + inv[i * 4 + 2] + inv[i * 4 + 3];
        #pragma unroll
        for (int i = 0; i < 3; i++) kp6s[t][3 + i] = ws[CAMT + (size_t)bv * 3 + i];
    }
    __syncthreads();
    // phase 1: hid = relu(kp6 @ kw1 + kb1) -> As (bf16), thread t owns column t
    {
        float w1j[6];
        #pragma unroll
        for (int i = 0; i < 6; i++) w1j[i] = kw1[i * C + t];
        float bb = kb1[t];
        for (int r = 0; r < VROWS; r++) {
            float h = bb;
            #pragma unroll
            for (int i = 0; i < 6; i++) h += kp6s[r][i] * w1j[i];
            As[r * ASTR + t] = tobf(fmaxf(h, 0.f));
        }
    }
    __syncthreads();
    int wave = t >> 6, lane = t & 63;
    int quad = lane >> 4, l15 = lane & 15;
    int mbase = wave * 16;                 // this wave owns rows [mbase, mbase+16)
    int rbase = mbase + quad * 4;          // first of this lane's 4 C-frag rows
    // prefetch feats for epilogue-1 (issued long before use -> latency hidden)
    float fpre[16][4];
    if (l0 + VROWS <= L) {
        #pragma unroll
        for (int nt = 0; nt < 16; nt++) {
            const float* fp = feats + ((size_t)bv * C + nt * 16 + l15) * L + l0 + rbase;
            #pragma unroll
            for (int u = 0; u < 4; u++) fpre[nt][u] = fp[u];
        }
    } else {
        #pragma unroll
        for (int nt = 0; nt < 16; nt++) {
            const float* fp = feats + ((size_t)bv * C + nt * 16 + l15) * L;
            #pragma unroll
            for (int u = 0; u < 4; u++) {
                int l = l0 + rbase + u;
                fpre[nt][u] = (l < L) ? fp[l] : 0.f;
            }
        }
    }
    floatx4 acc[16];
    // ---- GEMM1: vin = hid @ kw2 ----
    #pragma unroll
    for (int nt = 0; nt < 16; nt++) acc[nt] = (floatx4){0.f, 0.f, 0.f, 0.f};
    for (int kk = 0; kk < 8; kk++) {
        short8 a0 = *(const short8*)&As[(mbase + l15) * ASTR + kk * 32 + quad * 8];
        #pragma unroll
        for (int nt = 0; nt < 16; nt++) {
            short8 bfr = *(const short8*)&kw2T[(size_t)(nt * 16 + l15) * C + kk * 32 + quad * 8];
            acc[nt] = __builtin_amdgcn_mfma_f32_16x16x32_bf16(a0, bfr, acc[nt], 0, 0, 0);
        }
    }
    // epilogue 1: vin = acc + kb2 + feat -> back into As (wave-private rows)
    #pragma unroll
    for (int nt = 0; nt < 16; nt++) {
        int c = nt * 16 + l15;
        float bias = kb2[c];
        #pragma unroll
        for (int u = 0; u < 4; u++)
            As[(rbase + u) * ASTR + c] = tobf(acc[nt][u] + bias + fpre[nt][u]);
    }
    // ---- GEMM2: vals = vin @ dvw ----
    #pragma unroll
    for (int nt = 0; nt < 16; nt++) acc[nt] = (floatx4){0.f, 0.f, 0.f, 0.f};
    for (int kk = 0; kk < 8; kk++) {
        short8 a0 = *(const short8*)&As[(mbase + l15) * ASTR + kk * 32 + quad * 8];
        #pragma unroll
        for (int nt = 0; nt < 16; nt++) {
            short8 bfr = *(const short8*)&dvwT[(size_t)(nt * 16 + l15) * C + kk * 32 + quad * 8];
            acc[nt] = __builtin_amdgcn_mfma_f32_16x16x32_bf16(a0, bfr, acc[nt], 0, 0, 0);
        }
    }
    // epilogue 2: stage bf16 tile in LDS (own rows), then coalesced 16B store
    #pragma unroll
    for (int nt = 0; nt < 16; nt++) {
        int c = nt * 16 + l15;
        #pragma unroll
        for (int u = 0; u < 4; u++)
            As[(rbase + u) * ASTR + c] = tobf(acc[nt][u]);
    }
    __syncthreads();
    #pragma unroll
    for (int pass = 0; pass < 8; pass++) {
        int row = pass * 8 + (t >> 5);
        int col = (t & 31) * 8;
        int l = l0 + row;
        if (l < L)
            *(int4*)&vals[((size_t)bv * L + l) * C + col] = *(const int4*)&As[row * ASTR + col];
    }
}

// ---------------- deformable bilinear sampling + weighted sum ----------------
__global__ __launch_bounds__(256) void k_sample(const float* ws, const bf16* vals, float* wsmut) {
    int row = blockIdx.x, j = threadIdx.x;
    int h = j >> 5, d = j & 31;
    __shared__ float soff[256];
    __shared__ float sawL[128];
    __shared__ float sref[2];
    soff[j] = ws[OFFo + (size_t)row * 256 + j];
    if (j < 128) sawL[j] = ws[AWo + (size_t)row * 128 + j];
    if (j < 2) sref[j] = ws[REFo + (size_t)row * 2 + j];
    __syncthreads();
    int v = (row / P) % V, b = row / (P * V);
    const bf16* vbase = vals + (size_t)(b * V + v) * L * C + h * Dh + d;
    float acc = 0.f;
    for (int l = 0; l < NLEV; l++) {
        float Wf = (float)cLW[l], Hf = (float)cLH[l];
        int Wi = cLW[l], Hi = cLH[l], S0 = cLS[l];
        for (int n = 0; n < NPTS; n++) {
            int oi = ((h * NLEV + l) * NPTS + n) * 2;
            float lx = sref[0] + soff[oi + 0] / Wf;
            float ly = sref[1] + soff[oi + 1] / Hf;
            float aww = sawL[(h * NLEV + l) * NPTS + n];
            float x = lx * Wf - 0.5f, y = ly * Hf - 0.5f;
            float x0f = floorf(x), y0f = floorf(y);
            float wx = x - x0f, wy = y - y0f;
            int x0 = (int)x0f, y0 = (int)y0f;
            float s = 0.f;
            #pragma unroll
            for (int dy = 0; dy < 2; dy++) {
                #pragma unroll
                for (int dx = 0; dx < 2; dx++) {
                    int xi = x0 + dx, yi = y0 + dy;
                    if (xi >= 0 && xi < Wi && yi >= 0 && yi < Hi) {
                        float wwt = (dx ? wx : 1.f - wx) * (dy ? wy : 1.f - wy);
                        s += wwt * tof(vbase[(size_t)(S0 + yi * Wi + xi) * C]);
                    }
                }
            }
            acc += aww * s;
        }
    }
    wsmut[OUTSo + (size_t)row * C + j] = acc;
}

// ---------------- out @ dout_w + x1 + LN -> x2 ----------------
__global__ __launch_bounds__(256) void k_dout(const float* dw, float* ws) {
    int row = blockIdx.x, j = threadIdx.x;
    __shared__ __align__(16) float in[C];
    __shared__ float red[256];
    in[j] = ws[OUTSo + (size_t)row * C + j];
    __syncthreads();
    float t = dotK(in, dw, j, C, C);
    float r = ws[X1o + (size_t)row * C + j] + t;
    float mean = blockReduceSum(r, red) * (1.f / C);
    float diff = r - mean;
    float var = blockReduceSum(diff * diff, red) * (1.f / C);
    ws[X2o + (size_t)row * C + j] = diff * rsqrtf(var + 1e-5f);
}

// ---------------- FFN + LN -> x3  (8 rows per block, weights amortized) ----------------
constexpr int FR = 8;
__global__ __launch_bounds__(256, 3) void k_ffn(const float* __restrict__ w1, const float* __restrict__ b1,
                                                const float* __restrict__ w2, const float* __restrict__ b2,
                                                float* ws) {
    __shared__ __align__(16) float in_s[FR * C];     // x2 tile (8 KB)
    __shared__ __align__(16) float hid_s[FR * FFN];  // 32 KB
    __shared__ float redw[4][FR][2];
    __shared__ float mv[FR][2];
    int row0 = blockIdx.x * FR;
    int t = threadIdx.x;
    for (int i = t; i < FR * C / 4; i += 256)
        *(float4*)&in_s[i * 4] = *(const float4*)&ws[X2o + (size_t)row0 * C + i * 4];
    __syncthreads();
    // GEMM1 + relu -> hid_s ; thread t covers cols {t, t+256, t+512, t+768}
    for (int jj = 0; jj < 4; jj++) {
        int col = t + jj * 256;
        float acc8[FR];
        float bias = b1[col];
        #pragma unroll
        for (int r = 0; r < FR; r++) acc8[r] = bias;
        for (int k = 0; k < C; k += 4) {
            float wa = w1[(size_t)(k + 0) * FFN + col];
            float wb = w1[(size_t)(k + 1) * FFN + col];
            float wc = w1[(size_t)(k + 2) * FFN + col];
            float wd = w1[(size_t)(k + 3) * FFN + col];
            #pragma unroll
            for (int r = 0; r < FR; r++) {
                float4 x = *(const float4*)&in_s[r * C + k];
                acc8[r] += x.x * wa + x.y * wb + x.z * wc + x.w * wd;
            }
        }
        #pragma unroll
        for (int r = 0; r < FR; r++) hid_s[r * FFN + col] = fmaxf(acc8[r], 0.f);
    }
    __syncthreads();
    // GEMM2: thread t = output col t, 8 rows
    float acc8[FR];
    float bias2 = b2[t];
    #pragma unroll
    for (int r = 0; r < FR; r++) acc8[r] = bias2;
    for (int k = 0; k < FFN; k += 4) {
        float wa = w2[(size_t)(k + 0) * C + t];
        float wb = w2[(size_t)(k + 1) * C + t];
        float wc = w2[(size_t)(k + 2) * C + t];
        float wd = w2[(size_t)(k + 3) * C + t];
        #pragma unroll
        for (int r = 0; r < FR; r++) {
            float4 h = *(const float4*)&hid_s[r * FFN + k];
            acc8[r] += h.x * wa + h.y * wb + h.z * wc + h.w * wd;
        }
    }
    float rv[FR];
    #pragma unroll
    for (int r = 0; r < FR; r++) rv[r] = in_s[r * C + t] + acc8[r];
    // LN per row: wave shuffle-reduce then cross-wave via LDS
    int wv = t >> 6, lane = t & 63;
    #pragma unroll
    for (int r = 0; r < FR; r++) {
        float s = rv[r], q = rv[r] * rv[r];
        for (int off = 32; off > 0; off >>= 1) {
            s += __shfl_down(s, off, 64);
            q += __shfl_down(q, off, 64);
        }
        if (lane == 0) { redw[wv][r][0] = s; redw[wv][r][1] = q; }
    }
    __syncthreads();
    if (t < FR) {
        float s = redw[0][t][0] + redw[1][t][0] + redw[2][t][0] + redw[3][t][0];
        float q = redw[0][t][1] + redw[1][t][1] + redw[2][t][1] + redw[3][t][1];
        float mean = s * (1.f / C);
        float var = q * (1.f / C) - mean * mean;
        mv[t][0] = mean;
        mv[t][1] = rsqrtf(var + 1e-5f);
    }
    __syncthreads();
    #pragma unroll
    for (int r = 0; r < FR; r++)
        ws[X3o + (size_t)(row0 + r) * C + t] = (rv[r] - mv[r][0]) * mv[r][1];
}

// ---------------- masked view-mean + output0 ----------------
__global__ __launch_bounds__(256) void k_fuse(const int* maskin, float* ws, float* out) {
    int row = blockIdx.x, j = threadIdx.x;
    int b = row / P, p = row % P;
    float s = 0.f, cnt = 0.f;
    for (int v = 0; v < V; v++) {
        bool mk = (maskin[(b * P + p) * V + v] > 0) && (ws[MFLAG + b * V + v] > 0.5f);
        if (mk) {
            s += ws[X3o + ((size_t)((b * V + v) * P + p)) * C + j];
            cnt += 1.f;
        }
    }
    float f = s / (cnt + 1e-4f);
    ws[FUSEDo + (size_t)row * C + j] = f;
    out[O0 + ((size_t)b * C + j) * P + p] = f;
}

// ---------------- pred head + BEV outputs ----------------
__global__ __launch_bounds__(256) void k_pred(const float* w1, const float* b1, const float* w2, const float* b2,
                                              const float* qposin, float* ws, float* out) {
    int row = blockIdx.x, j = threadIdx.x;
    __shared__ __align__(16) float in[C];
    __shared__ float red[256];
    __shared__ float cen[4];
    in[j] = ws[FUSEDo + (size_t)row * C + j];
    __syncthreads();
    float h = fmaxf(b1[j] + dotK(in, w1, j, C, C), 0.f);
    for (int i = 0; i < 3; i++) {
        float s = blockReduceSum(h * w2[j * 3 + i], red);
        if (j == 0) cen[i] = s + b2[i] + qposin[row * 3 + i];
    }
    if (j == 0) {
        float c0 = cen[0], c1 = cen[1], c2 = cen[2];
        float cx = (c0 + 54.f) / 108.f * 135.f;
        float cy = (c1 + 54.f) / 108.f * 135.f;
        int b = row / P, p = row % P;
        out[O1 + (size_t)row * 3 + 0] = c0;
        out[O1 + (size_t)row * 3 + 1] = c1;
        out[O1 + (size_t)row * 3 + 2] = c2;
        out[O2 + (size_t)row * 2 + 0] = cx;
        out[O2 + (size_t)row * 2 + 1] = cy;
        out[O3 + (size_t)b * 2 * P + 0 * P + p] = cx;
        out[O3 + (size_t)b * 2 * P + 1 * P + p] = cy;
        out[O4 + (size_t)b * P + p] = c2;
    }
}

extern "C" void kernel_launch(void* const* d_in, const int* in_sizes, int n_in,
                              void* d_out, int out_size, void* d_ws, size_t ws_size,
                              hipStream_t stream) {
    const float* qfeat  = (const float*)d_in[0];
    const float* qposin = (const float*)d_in[1];
    const int*   maskin = (const int*)d_in[2];
    const float* feats  = (const float*)d_in[3];
    const float* npos   = (const float*)d_in[4];
    const float* rt     = (const float*)d_in[5];
    const float* l2cr   = (const float*)d_in[6];
    const float* l2ct   = (const float*)d_in[7];
    const float* qp_w1 = (const float*)d_in[8],  * qp_b1 = (const float*)d_in[9];
    const float* qp_w2 = (const float*)d_in[10], * qp_b2 = (const float*)d_in[11];
    const float* kp_w1 = (const float*)d_in[12], * kp_b1 = (const float*)d_in[13];
    const float* kp_w2 = (const float*)d_in[14], * kp_b2 = (const float*)d_in[15];
    const float* sa_wq = (const float*)d_in[16], * sa_wk = (const float*)d_in[17];
    const float* sa_wv = (const float*)d_in[18], * sa_wo = (const float*)d_in[19];
    const float* dv_w  = (const float*)d_in[20];
    const float* doffw = (const float*)d_in[21], * doffb = (const float*)d_in[22];
    const float* dattw = (const float*)d_in[23], * dattb = (const float*)d_in[24];
    const float* doutw = (const float*)d_in[25];
    const float* f_w1  = (const float*)d_in[26], * f_b1 = (const float*)d_in[27];
    const float* f_w2  = (const float*)d_in[28], * f_b2 = (const float*)d_in[29];
    const float* p_w1  = (const float*)d_in[30], * p_b1 = (const float*)d_in[31];
    const float* p_w2  = (const float*)d_in[32], * p_b2 = (const float*)d_in[33];

    float* ws = (float*)d_ws;
    bf16* vals = (bf16*)((char*)d_ws + VALS_BYTE_OFF);
    bf16* kw2T = vals + VALS_ELEMS;
    bf16* dvwT = kw2T + (size_t)C * C;
    float* out = (float*)d_out;

    k_setup<<<1, 64, 0, stream>>>(rt, l2cr, l2ct, maskin, ws);
    k_wprep<<<512, 256, 0, stream>>>(kp_w2, dv_w, kw2T, dvwT);
    k_qpos<<<BP, 256, 0, stream>>>(qfeat, qposin, qp_w1, qp_b1, qp_w2, qp_b2, ws);
    k_qkv<<<dim3(BP, 3), 256, 0, stream>>>(sa_wq, sa_wk, sa_wv, ws);
    k_logits<<<B * HH * P, 256, 0, stream>>>(ws);
    k_sattn<<<B * V * HH * P, 256, 0, stream>>>(maskin, ws);
    k_saout<<<BVP, 256, 0, stream>>>(sa_wo, ws);
    k_ref<<<(BVP + 255) / 256, 256, 0, stream>>>(qposin, rt, ws);
    k_offaw<<<BVP, 256, 0, stream>>>(doffw, doffb, dattw, dattb, ws);
    k_vals_mfma<<<dim3(NVT, BV), 256, 0, stream>>>(npos, feats, kp_w1, kp_b1, kp_b2, kw2T, dvwT, ws, vals);
    k_sample<<<BVP, 256, 0, stream>>>(ws, vals, ws);
    k_dout<<<BVP, 256, 0, stream>>>(doutw, ws);
    k_ffn<<<BVP / FR, 256, 0, stream>>>(f_w1, f_b1, f_w2, f_b2, ws);
    k_fuse<<<BP, 256, 0, stream>>>(maskin, ws, out);
    k_pred<<<BP, 256, 0, stream>>>(p_w1, p_b1, p_w2, p_b2, qposin, ws, out);
}

// Round 5
// 1053.649 us; speedup vs baseline: 1.8902x; 1.1201x over previous
//
#include <hip/hip_runtime.h>
#include <hip/hip_bf16.h>
#include <cstdint>
#include <cstddef>

using bf16 = __hip_bfloat16;
#define DEVFN static __device__ __forceinline__

constexpr int B = 4, V = 6, P = 200, C = 256, HH = 8, Dh = 32, NLEV = 4, NPTS = 4, FFN = 1024;
constexpr int L = 7441;
constexpr int BV = B * V, BP = B * P, BVP = B * V * P, BVL = B * V * L;
constexpr float IMG_W = 800.f, IMG_H = 448.f;

__constant__ int cLH[4] = {56, 28, 14, 7};
__constant__ int cLW[4] = {100, 50, 25, 13};
__constant__ int cLS[4] = {0, 5600, 7000, 7350};

// ---- workspace layout (offsets in floats) ----
constexpr size_t IRT   = 0;
constexpr size_t CAMT  = IRT + (size_t)BV * 16;
constexpr size_t MFLAG = CAMT + (size_t)BV * 3;
constexpr size_t Xo    = MFLAG + BV;
constexpr size_t QPOSo = Xo + (size_t)BP * C;
constexpr size_t Qo    = QPOSo + (size_t)BP * C;
constexpr size_t Ko    = Qo + (size_t)BP * C;
constexpr size_t VVo   = Ko + (size_t)BP * C;
constexpr size_t LOGo  = VVo + (size_t)BP * C;
constexpr size_t SAo   = LOGo + (size_t)B * HH * P * P;
constexpr size_t X1o   = SAo + (size_t)BVP * C;
constexpr size_t REFo  = X1o + (size_t)BVP * C;
constexpr size_t OFFo  = REFo + (size_t)BVP * 2;
constexpr size_t AWo   = OFFo + (size_t)BVP * 256;
constexpr size_t OUTSo = AWo + (size_t)BVP * 128;
constexpr size_t X2o   = OUTSo + (size_t)BVP * C;
constexpr size_t X3o   = X2o + (size_t)BVP * C;
constexpr size_t FUSEDo= X3o + (size_t)BVP * C;
constexpr size_t WS_FLOATS = FUSEDo + (size_t)BP * C;
constexpr size_t VALS_BYTE_OFF = ((WS_FLOATS * 4 + 255) / 256) * 256;
constexpr size_t VALS_ELEMS = (size_t)BVL * C;   // bf16

// ---- output layout (elements, f32) ----
constexpr size_t O0 = 0;                          // (B,C,P)
constexpr size_t O1 = O0 + (size_t)B * C * P;     // (B,P,3)
constexpr size_t O2 = O1 + (size_t)B * P * 3;     // (B,P,2)
constexpr size_t O3 = O2 + (size_t)B * P * 2;     // (B,2,P)
constexpr size_t O4 = O3 + (size_t)B * 2 * P;     // (B,1,P)

DEVFN float tof(bf16 x) { return __bfloat162float(x); }
DEVFN bf16  tobf(float x) { return __float2bfloat16(x); }

typedef __attribute__((ext_vector_type(8))) short short8;
typedef __attribute__((ext_vector_type(4))) float floatx4;

DEVFN float blockReduceSum(float v, float* red) {
    int j = threadIdx.x;
    __syncthreads();
    red[j] = v; __syncthreads();
    for (int s = 128; s > 0; s >>= 1) { if (j < s) red[j] += red[j + s]; __syncthreads(); }
    return red[0];
}
DEVFN float blockReduceMax(float v, float* red) {
    int j = threadIdx.x;
    __syncthreads();
    red[j] = v; __syncthreads();
    for (int s = 128; s > 0; s >>= 1) { if (j < s) red[j] = fmaxf(red[j], red[j + s]); __syncthreads(); }
    return red[0];
}

// out_j = sum_k s[k] * W[k*N + j]   (W f32 row-major (K,N), s in LDS)
DEVFN float dotK(const float* __restrict__ s, const float* __restrict__ W, int j, int N, int K) {
    float acc = 0.f;
    for (int k = 0; k < K; k += 4) {
        float4 h = *(const float4*)(s + k);
        acc += h.x * W[(size_t)(k + 0) * N + j];
        acc += h.y * W[(size_t)(k + 1) * N + j];
        acc += h.z * W[(size_t)(k + 2) * N + j];
        acc += h.w * W[(size_t)(k + 3) * N + j];
    }
    return acc;
}

// ---------------- setup: inverse(rt), cam_t, view-valid flag ----------------
__global__ __launch_bounds__(64) void k_setup(const float* rt, const float* l2cr, const float* l2ct,
                                              const int* maskin, float* ws) {
    int t = threadIdx.x;
    if (t >= BV) return;
    float m[16], inv[16];
    for (int i = 0; i < 16; i++) m[i] = rt[t * 16 + i];
    inv[0]  =  m[5]*m[10]*m[15] - m[5]*m[11]*m[14] - m[9]*m[6]*m[15] + m[9]*m[7]*m[14] + m[13]*m[6]*m[11] - m[13]*m[7]*m[10];
    inv[4]  = -m[4]*m[10]*m[15] + m[4]*m[11]*m[14] + m[8]*m[6]*m[15] - m[8]*m[7]*m[14] - m[12]*m[6]*m[11] + m[12]*m[7]*m[10];
    inv[8]  =  m[4]*m[9]*m[15]  - m[4]*m[11]*m[13] - m[8]*m[5]*m[15] + m[8]*m[7]*m[13] + m[12]*m[5]*m[11] - m[12]*m[7]*m[9];
    inv[12] = -m[4]*m[9]*m[14]  + m[4]*m[10]*m[13] + m[8]*m[5]*m[14] - m[8]*m[6]*m[13] - m[12]*m[5]*m[10] + m[12]*m[6]*m[9];
    inv[1]  = -m[1]*m[10]*m[15] + m[1]*m[11]*m[14] + m[9]*m[2]*m[15] - m[9]*m[3]*m[14] - m[13]*m[2]*m[11] + m[13]*m[3]*m[10];
    inv[5]  =  m[0]*m[10]*m[15] - m[0]*m[11]*m[14] - m[8]*m[2]*m[15] + m[8]*m[3]*m[14] + m[12]*m[2]*m[11] - m[12]*m[3]*m[10];
    inv[9]  = -m[0]*m[9]*m[15]  + m[0]*m[11]*m[13] + m[8]*m[1]*m[15] - m[8]*m[3]*m[13] - m[12]*m[1]*m[11] + m[12]*m[3]*m[9];
    inv[13] =  m[0]*m[9]*m[14]  - m[0]*m[10]*m[13] - m[8]*m[1]*m[14] + m[8]*m[2]*m[13] + m[12]*m[1]*m[10] - m[12]*m[2]*m[9];
    inv[2]  =  m[1]*m[6]*m[15]  - m[1]*m[7]*m[14]  - m[5]*m[2]*m[15] + m[5]*m[3]*m[14] + m[13]*m[2]*m[7]  - m[13]*m[3]*m[6];
    inv[6]  = -m[0]*m[6]*m[15]  + m[0]*m[7]*m[14]  + m[4]*m[2]*m[15] - m[4]*m[3]*m[14] - m[12]*m[2]*m[7]  + m[12]*m[3]*m[6];
    inv[10] =  m[0]*m[5]*m[15]  - m[0]*m[7]*m[13]  - m[4]*m[1]*m[15] + m[4]*m[3]*m[13] + m[12]*m[1]*m[7]  - m[12]*m[3]*m[5];
    inv[14] = -m[0]*m[5]*m[14]  + m[0]*m[6]*m[13]  + m[4]*m[1]*m[14] - m[4]*m[2]*m[13] - m[12]*m[1]*m[6]  + m[12]*m[2]*m[5];
    inv[3]  = -m[1]*m[6]*m[11]  + m[1]*m[7]*m[10]  + m[5]*m[2]*m[11] - m[5]*m[3]*m[10] - m[9]*m[2]*m[7]   + m[9]*m[3]*m[6];
    inv[7]  =  m[0]*m[6]*m[11]  - m[0]*m[7]*m[10]  - m[4]*m[2]*m[11] + m[4]*m[3]*m[10] + m[8]*m[2]*m[7]   - m[8]*m[3]*m[6];
    inv[11] = -m[0]*m[5]*m[11]  + m[0]*m[7]*m[9]   + m[4]*m[1]*m[11] - m[4]*m[3]*m[9]  - m[8]*m[1]*m[7]   + m[8]*m[3]*m[5];
    inv[15] =  m[0]*m[5]*m[10]  - m[0]*m[6]*m[9]   - m[4]*m[1]*m[10] + m[4]*m[2]*m[9]  + m[8]*m[1]*m[6]   - m[8]*m[2]*m[5];
    float det = m[0]*inv[0] + m[1]*inv[4] + m[2]*inv[8] + m[3]*inv[12];
    float rd = 1.f / det;
    for (int i = 0; i < 16; i++) ws[IRT + t * 16 + i] = inv[i] * rd;
    float r9[9], tv[3];
    for (int i = 0; i < 9; i++) r9[i] = l2cr[t * 9 + i];
    for (int i = 0; i < 3; i++) tv[i] = l2ct[t * 3 + i];
    for (int i = 0; i < 3; i++)
        ws[CAMT + t * 3 + i] = -(r9[0 * 3 + i] * tv[0] + r9[1 * 3 + i] * tv[1] + r9[2 * 3 + i] * tv[2]);
    int b = t / V, v = t % V, cnt = 0;
    for (int p = 0; p < P; p++) cnt += (maskin[(b * P + p) * V + v] > 0) ? 1 : 0;
    ws[MFLAG + t] = (cnt > 1) ? 1.f : 0.f;
}

// ---------------- weight prep: transpose + bf16 cast for MFMA B operands ----------------
__global__ __launch_bounds__(256) void k_wprep(const float* kw2, const float* dvw, bf16* kw2T, bf16* dvwT) {
    int n = blockIdx.x & 255;
    int k = threadIdx.x;
    if (blockIdx.x < 256) kw2T[n * 256 + k] = tobf(kw2[(size_t)k * 256 + n]);
    else                  dvwT[n * 256 + k] = tobf(dvw[(size_t)k * 256 + n]);
}

// ---------------- qpos MLP + x transpose ----------------
__global__ __launch_bounds__(256) void k_qpos(const float* qfeat, const float* qposin,
                                              const float* w1, const float* b1, const float* w2, const float* b2,
                                              float* ws) {
    int row = blockIdx.x, j = threadIdx.x;
    int b = row / P, p = row % P;
    __shared__ __align__(16) float pos[4];
    __shared__ __align__(16) float hid[C];
    if (j < 3) pos[j] = qposin[row * 3 + j];
    __syncthreads();
    float h = b1[j] + pos[0] * w1[0 * C + j] + pos[1] * w1[1 * C + j] + pos[2] * w1[2 * C + j];
    hid[j] = fmaxf(h, 0.f);
    __syncthreads();
    float acc = b2[j] + dotK(hid, w2, j, C, C);
    ws[QPOSo + (size_t)row * C + j] = acc;
    ws[Xo + (size_t)row * C + j] = qfeat[((size_t)b * C + j) * P + p];
}

// ---------------- q / k / v projections ----------------
__global__ __launch_bounds__(256) void k_qkv(const float* wq, const float* wk, const float* wv, float* ws) {
    int row = blockIdx.x, which = blockIdx.y, j = threadIdx.x;
    __shared__ __align__(16) float in[C];
    float xv = ws[Xo + (size_t)row * C + j];
    in[j] = (which < 2) ? (xv + ws[QPOSo + (size_t)row * C + j]) : xv;
    __syncthreads();
    const float* W = (which == 0) ? wq : (which == 1) ? wk : wv;
    float acc = dotK(in, W, j, C, C);
    size_t dst = (which == 0) ? Qo : (which == 1) ? Ko : VVo;
    ws[dst + (size_t)row * C + j] = acc;
}

// ---------------- attention logits ----------------
__global__ __launch_bounds__(256) void k_logits(float* ws) {
    int bid = blockIdx.x;          // (b*HH + h)*P + qi
    int qi = bid % P, h = (bid / P) % HH, b = bid / (P * HH);
    int j = threadIdx.x;
    __shared__ __align__(16) float qf[Dh];
    if (j < Dh) qf[j] = ws[Qo + ((size_t)(b * P + qi)) * C + h * Dh + j];
    __syncthreads();
    if (j < P) {
        const float* kp = ws + Ko + ((size_t)(b * P + j)) * C + h * Dh;
        float acc = 0.f;
        for (int d = 0; d < Dh; d += 4) {
            float4 kv = *(const float4*)(kp + d);
            float4 qv = *(const float4*)(qf + d);
            acc += kv.x * qv.x + kv.y * qv.y + kv.z * qv.z + kv.w * qv.w;
        }
        ws[LOGo + (size_t)bid * P + j] = acc * 0.17677669529663687f;
    }
}

// ---------------- masked softmax + attn @ V ----------------
__global__ __launch_bounds__(256) void k_sattn(const int* maskin, float* ws) {
    int bid = blockIdx.x;          // ((b*V+v)*HH + h)*P + qi
    int qi = bid % P, h = (bid / P) % HH, v = (bid / (P * HH)) % V, b = bid / (P * HH * V);
    int j = threadIdx.x;
    __shared__ float attn[256];
    __shared__ float red[256];
    float flag = ws[MFLAG + b * V + v];
    float val = -1e30f;
    if (j < P) {
        float lg = ws[LOGo + ((size_t)(b * HH + h) * P + qi) * P + j];
        bool mk = (flag > 0.5f) && (maskin[(b * P + j) * V + v] > 0);
        val = lg + (mk ? 0.f : -1e9f);
    }
    float mx = blockReduceMax(val, red);
    float e = (j < P) ? __expf(val - mx) : 0.f;
    float s = blockReduceSum(e, red);
    attn[j] = e / s;
    __syncthreads();
    int d = j & 31, c = j >> 5;
    const float* vvp = ws + VVo + (size_t)b * P * C + h * Dh + d;
    float acc = 0.f;
    for (int kk = c * 25; kk < c * 25 + 25; ++kk) acc += attn[kk] * vvp[(size_t)kk * C];
    red[j] = acc; __syncthreads();
    if (j < Dh) {
        float s2 = 0.f;
        for (int c2 = 0; c2 < 8; c2++) s2 += red[c2 * 32 + j];
        ws[SAo + ((size_t)((b * V + v) * P + qi)) * C + h * Dh + j] = s2;
    }
}

// ---------------- sa @ wo + residual + LN -> x1 ----------------
__global__ __launch_bounds__(256) void k_saout(const float* wo, float* ws) {
    int row = blockIdx.x, j = threadIdx.x;
    int p = row % P, b = row / (P * V);
    __shared__ __align__(16) float in[C];
    __shared__ float red[256];
    in[j] = ws[SAo + (size_t)row * C + j];
    __syncthreads();
    float t = dotK(in, wo, j, C, C);
    float r = ws[Xo + ((size_t)(b * P + p)) * C + j] + t;
    float mean = blockReduceSum(r, red) * (1.f / C);
    float diff = r - mean;
    float var = blockReduceSum(diff * diff, red) * (1.f / C);
    ws[X1o + (size_t)row * C + j] = diff * rsqrtf(var + 1e-5f);
}

// ---------------- reference points ----------------
__global__ __launch_bounds__(256) void k_ref(const float* qposin, const float* rt, float* ws) {
    int tid = blockIdx.x * 256 + threadIdx.x;
    if (tid >= BVP) return;
    int p = tid % P, v = (tid / P) % V, b = tid / (P * V);
    float p0 = qposin[(b * P + p) * 3 + 0];
    float p1 = qposin[(b * P + p) * 3 + 1];
    float p2 = qposin[(b * P + p) * 3 + 2];
    const float* m = rt + (size_t)(b * V + v) * 16;
    float pr[3];
    for (int i = 0; i < 3; i++)
        pr[i] = m[i * 4 + 0] * p0 + m[i * 4 + 1] * p1 + m[i * 4 + 2] * p2 + m[i * 4 + 3];
    ws[REFo + (size_t)tid * 2 + 0] = pr[0] / pr[2] / IMG_W;
    ws[REFo + (size_t)tid * 2 + 1] = pr[1] / pr[2] / IMG_H;
}

// ---------------- offsets + attention weights heads ----------------
__global__ __launch_bounds__(256) void k_offaw(const float* ow, const float* ob, const float* aw_w, const float* aw_b,
                                               float* ws) {
    int row = blockIdx.x, j = threadIdx.x;
    int p = row % P, b = row / (P * V);
    __shared__ __align__(16) float q2[C];
    __shared__ float al[128];
    q2[j] = ws[X1o + (size_t)row * C + j] + ws[QPOSo + ((size_t)(b * P + p)) * C + j];
    __syncthreads();
    float offv = ob[j] + dotK(q2, ow, j, 256, C);
    ws[OFFo + (size_t)row * 256 + j] = offv;
    if (j < 128) al[j] = aw_b[j] + dotK(q2, aw_w, j, 128, C);
    __syncthreads();
    if (j < 128) {
        int g = (j >> 4) << 4;
        float mx = -1e30f;
        for (int i = 0; i < 16; i++) mx = fmaxf(mx, al[g + i]);
        float s = 0.f;
        for (int i = 0; i < 16; i++) s += __expf(al[g + i] - mx);
        ws[AWo + (size_t)row * 128 + j] = __expf(al[j] - mx) / s;
    }
}

// ---------------- vals via MFMA v3: N-split waves, LDS feat-add pass ----------------
constexpr int VROWS = 64;
constexpr int ASTR = C + 8;                     // 264 elems -> 528 B row stride
constexpr int NVT = (L + VROWS - 1) / VROWS;    // 117

__global__ __launch_bounds__(256, 4) void k_vals_mfma(
        const float* __restrict__ npos, const float* __restrict__ feats,
        const float* __restrict__ kw1, const float* __restrict__ kb1, const float* __restrict__ kb2,
        const bf16* __restrict__ kw2T, const bf16* __restrict__ dvwT,
        const float* __restrict__ ws, bf16* __restrict__ vals) {
    __shared__ __align__(16) bf16 As[VROWS * ASTR];
    __shared__ float kp6s[VROWS][8];
    __shared__ float kb2s[C];
    int bv = blockIdx.y;
    int l0 = blockIdx.x * VROWS;
    int t = threadIdx.x;
    // phase 0: per-row 6-dim key_pos + kb2 preload
    kb2s[t] = kb2[t];
    if (t < VROWS) {
        int l = min(l0 + t, L - 1);
        float sx = 1.f / (1.f + __expf(-npos[l * 2 + 0])) * IMG_W;
        float sy = 1.f / (1.f + __expf(-npos[l * 2 + 1])) * IMG_H;
        const float* inv = ws + IRT + (size_t)bv * 16;
        #pragma unroll
        for (int i = 0; i < 3; i++)
            kp6s[t][i] = inv[i * 4 + 0] * sx + inv[i * 4 + 1] * sy + inv[i * 4 + 2] + inv[i * 4 + 3];
        #pragma unroll
        for (int i = 0; i < 3; i++) kp6s[t][3 + i] = ws[CAMT + (size_t)bv * 3 + i];
    }
    __syncthreads();
    // phase 1: hid = relu(kp6 @ kw1 + kb1) -> As, thread t owns column t
    {
        float w1j[6];
        #pragma unroll
        for (int i = 0; i < 6; i++) w1j[i] = kw1[i * C + t];
        float bb = kb1[t];
        for (int r = 0; r < VROWS; r++) {
            float h = bb;
            #pragma unroll
            for (int i = 0; i < 6; i++) h += kp6s[r][i] * w1j[i];
            As[r * ASTR + t] = tobf(fmaxf(h, 0.f));
        }
    }
    __syncthreads();
    int wave = t >> 6, lane = t & 63;
    int quad = lane >> 4, l15 = lane & 15;
    int mh = (wave >> 1) * 32;      // wave's 32-row half
    int nh = (wave & 1) * 128;      // wave's 128-col half
    floatx4 acc[2][8];
    // ---- GEMM1: vin = hid @ kw2 ----
    #pragma unroll
    for (int i = 0; i < 2; i++)
        #pragma unroll
        for (int nt = 0; nt < 8; nt++) acc[i][nt] = (floatx4){0.f, 0.f, 0.f, 0.f};
    for (int kk = 0; kk < 8; kk++) {
        short8 a0 = *(const short8*)&As[(mh + l15) * ASTR + kk * 32 + quad * 8];
        short8 a1 = *(const short8*)&As[(mh + 16 + l15) * ASTR + kk * 32 + quad * 8];
        #pragma unroll
        for (int nt = 0; nt < 8; nt++) {
            short8 bfr = *(const short8*)&kw2T[(size_t)(nh + nt * 16 + l15) * C + kk * 32 + quad * 8];
            acc[0][nt] = __builtin_amdgcn_mfma_f32_16x16x32_bf16(a0, bfr, acc[0][nt], 0, 0, 0);
            acc[1][nt] = __builtin_amdgcn_mfma_f32_16x16x32_bf16(a1, bfr, acc[1][nt], 0, 0, 0);
        }
    }
    __syncthreads();   // all waves done reading As
    // epilogue 1: write own (mh, nh) quadrant (bias+feat added next pass)
    #pragma unroll
    for (int i = 0; i < 2; i++) {
        #pragma unroll
        for (int nt = 0; nt < 8; nt++) {
            int c = nh + nt * 16 + l15;
            int rb = mh + i * 16 + quad * 4;
            #pragma unroll
            for (int u = 0; u < 4; u++)
                As[(rb + u) * ASTR + c] = tobf(acc[i][nt][u]);
        }
    }
    __syncthreads();
    // feat-add pass: As[l][c] += kb2[c] + feats[bv][c][l0+l]  (coalesced float4 reads)
    if (l0 + VROWS <= L) {
        #pragma unroll
        for (int round = 0; round < 16; round++) {
            int q = round * 256 + t;
            int c = q >> 4, ql = (q & 15) * 4;
            float4 f = *(const float4*)&feats[((size_t)bv * C + c) * L + l0 + ql];
            float bias = kb2s[c];
            int a0i = ql * ASTR + c;
            As[a0i]            = tobf(tof(As[a0i])            + bias + f.x);
            As[a0i + ASTR]     = tobf(tof(As[a0i + ASTR])     + bias + f.y);
            As[a0i + 2 * ASTR] = tobf(tof(As[a0i + 2 * ASTR]) + bias + f.z);
            As[a0i + 3 * ASTR] = tobf(tof(As[a0i + 3 * ASTR]) + bias + f.w);
        }
    } else {
        for (int round = 0; round < 16; round++) {
            int q = round * 256 + t;
            int c = q >> 4, ql = (q & 15) * 4;
            float bias = kb2s[c];
            #pragma unroll
            for (int u = 0; u < 4; u++) {
                int l = l0 + ql + u;
                if (l < L) {
                    int ai = (ql + u) * ASTR + c;
                    As[ai] = tobf(tof(As[ai]) + bias + feats[((size_t)bv * C + c) * L + l]);
                }
            }
        }
    }
    __syncthreads();
    // ---- GEMM2: vals = vin @ dvw ----
    #pragma unroll
    for (int i = 0; i < 2; i++)
        #pragma unroll
        for (int nt = 0; nt < 8; nt++) acc[i][nt] = (floatx4){0.f, 0.f, 0.f, 0.f};
    for (int kk = 0; kk < 8; kk++) {
        short8 a0 = *(const short8*)&As[(mh + l15) * ASTR + kk * 32 + quad * 8];
        short8 a1 = *(const short8*)&As[(mh + 16 + l15) * ASTR + kk * 32 + quad * 8];
        #pragma unroll
        for (int nt = 0; nt < 8; nt++) {
            short8 bfr = *(const short8*)&dvwT[(size_t)(nh + nt * 16 + l15) * C + kk * 32 + quad * 8];
            acc[0][nt] = __builtin_amdgcn_mfma_f32_16x16x32_bf16(a0, bfr, acc[0][nt], 0, 0, 0);
            acc[1][nt] = __builtin_amdgcn_mfma_f32_16x16x32_bf16(a1, bfr, acc[1][nt], 0, 0, 0);
        }
    }
    __syncthreads();
    // epilogue 2: stage bf16 tile, then coalesced 16B store
    #pragma unroll
    for (int i = 0; i < 2; i++) {
        #pragma unroll
        for (int nt = 0; nt < 8; nt++) {
            int c = nh + nt * 16 + l15;
            int rb = mh + i * 16 + quad * 4;
            #pragma unroll
            for (int u = 0; u < 4; u++)
                As[(rb + u) * ASTR + c] = tobf(acc[i][nt][u]);
        }
    }
    __syncthreads();
    #pragma unroll
    for (int pass = 0; pass < 8; pass++) {
        int row = pass * 8 + (t >> 5);
        int col = (t & 31) * 8;
        int l = l0 + row;
        if (l < L)
            *(int4*)&vals[((size_t)bv * L + l) * C + col] = *(const int4*)&As[row * ASTR + col];
    }
}

// ---------------- deformable bilinear sampling + weighted sum ----------------
__global__ __launch_bounds__(256) void k_sample(const float* ws, const bf16* vals, float* wsmut) {
    int row = blockIdx.x, j = threadIdx.x;
    int h = j >> 5, d = j & 31;
    __shared__ float soff[256];
    __shared__ float sawL[128];
    __shared__ float sref[2];
    soff[j] = ws[OFFo + (size_t)row * 256 + j];
    if (j < 128) sawL[j] = ws[AWo + (size_t)row * 128 + j];
    if (j < 2) sref[j] = ws[REFo + (size_t)row * 2 + j];
    __syncthreads();
    int v = (row / P) % V, b = row / (P * V);
    const bf16* vbase = vals + (size_t)(b * V + v) * L * C + h * Dh + d;
    float acc = 0.f;
    for (int l = 0; l < NLEV; l++) {
        float Wf = (float)cLW[l], Hf = (float)cLH[l];
        int Wi = cLW[l], Hi = cLH[l], S0 = cLS[l];
        for (int n = 0; n < NPTS; n++) {
            int oi = ((h * NLEV + l) * NPTS + n) * 2;
            float lx = sref[0] + soff[oi + 0] / Wf;
            float ly = sref[1] + soff[oi + 1] / Hf;
            float aww = sawL[(h * NLEV + l) * NPTS + n];
            float x = lx * Wf - 0.5f, y = ly * Hf - 0.5f;
            float x0f = floorf(x), y0f = floorf(y);
            float wx = x - x0f, wy = y - y0f;
            int x0 = (int)x0f, y0 = (int)y0f;
            float s = 0.f;
            #pragma unroll
            for (int dy = 0; dy < 2; dy++) {
                #pragma unroll
                for (int dx = 0; dx < 2; dx++) {
                    int xi = x0 + dx, yi = y0 + dy;
                    if (xi >= 0 && xi < Wi && yi >= 0 && yi < Hi) {
                        float wwt = (dx ? wx : 1.f - wx) * (dy ? wy : 1.f - wy);
                        s += wwt * tof(vbase[(size_t)(S0 + yi * Wi + xi) * C]);
                    }
                }
            }
            acc += aww * s;
        }
    }
    wsmut[OUTSo + (size_t)row * C + j] = acc;
}

// ---------------- out @ dout_w + x1 + LN -> x2 ----------------
__global__ __launch_bounds__(256) void k_dout(const float* dw, float* ws) {
    int row = blockIdx.x, j = threadIdx.x;
    __shared__ __align__(16) float in[C];
    __shared__ float red[256];
    in[j] = ws[OUTSo + (size_t)row * C + j];
    __syncthreads();
    float t = dotK(in, dw, j, C, C);
    float r = ws[X1o + (size_t)row * C + j] + t;
    float mean = blockReduceSum(r, red) * (1.f / C);
    float diff = r - mean;
    float var = blockReduceSum(diff * diff, red) * (1.f / C);
    ws[X2o + (size_t)row * C + j] = diff * rsqrtf(var + 1e-5f);
}

// ---------------- FFN + LN -> x3  (8 rows per block, weights amortized) ----------------
constexpr int FR = 8;
__global__ __launch_bounds__(256, 3) void k_ffn(const float* __restrict__ w1, const float* __restrict__ b1,
                                                const float* __restrict__ w2, const float* __restrict__ b2,
                                                float* ws) {
    __shared__ __align__(16) float in_s[FR * C];
    __shared__ __align__(16) float hid_s[FR * FFN];
    __shared__ float redw[4][FR][2];
    __shared__ float mv[FR][2];
    int row0 = blockIdx.x * FR;
    int t = threadIdx.x;
    for (int i = t; i < FR * C / 4; i += 256)
        *(float4*)&in_s[i * 4] = *(const float4*)&ws[X2o + (size_t)row0 * C + i * 4];
    __syncthreads();
    for (int jj = 0; jj < 4; jj++) {
        int col = t + jj * 256;
        float acc8[FR];
        float bias = b1[col];
        #pragma unroll
        for (int r = 0; r < FR; r++) acc8[r] = bias;
        for (int k = 0; k < C; k += 4) {
            float wa = w1[(size_t)(k + 0) * FFN + col];
            float wb = w1[(size_t)(k + 1) * FFN + col];
            float wc = w1[(size_t)(k + 2) * FFN + col];
            float wd = w1[(size_t)(k + 3) * FFN + col];
            #pragma unroll
            for (int r = 0; r < FR; r++) {
                float4 x = *(const float4*)&in_s[r * C + k];
                acc8[r] += x.x * wa + x.y * wb + x.z * wc + x.w * wd;
            }
        }
        #pragma unroll
        for (int r = 0; r < FR; r++) hid_s[r * FFN + col] = fmaxf(acc8[r], 0.f);
    }
    __syncthreads();
    float acc8[FR];
    float bias2 = b2[t];
    #pragma unroll
    for (int r = 0; r < FR; r++) acc8[r] = bias2;
    for (int k = 0; k < FFN; k += 4) {
        float wa = w2[(size_t)(k + 0) * C + t];
        float wb = w2[(size_t)(k + 1) * C + t];
        float wc = w2[(size_t)(k + 2) * C + t];
        float wd = w2[(size_t)(k + 3) * C + t];
        #pragma unroll
        for (int r = 0; r < FR; r++) {
            float4 h = *(const float4*)&hid_s[r * FFN + k];
            acc8[r] += h.x * wa + h.y * wb + h.z * wc + h.w * wd;
        }
    }
    float rv[FR];
    #pragma unroll
    for (int r = 0; r < FR; r++) rv[r] = in_s[r * C + t] + acc8[r];
    int wv = t >> 6, lane = t & 63;
    #pragma unroll
    for (int r = 0; r < FR; r++) {
        float s = rv[r], q = rv[r] * rv[r];
        for (int off = 32; off > 0; off >>= 1) {
            s += __shfl_down(s, off, 64);
            q += __shfl_down(q, off, 64);
        }
        if (lane == 0) { redw[wv][r][0] = s; redw[wv][r][1] = q; }
    }
    __syncthreads();
    if (t < FR) {
        float s = redw[0][t][0] + redw[1][t][0] + redw[2][t][0] + redw[3][t][0];
        float q = redw[0][t][1] + redw[1][t][1] + redw[2][t][1] + redw[3][t][1];
        float mean = s * (1.f / C);
        float var = q * (1.f / C) - mean * mean;
        mv[t][0] = mean;
        mv[t][1] = rsqrtf(var + 1e-5f);
    }
    __syncthreads();
    #pragma unroll
    for (int r = 0; r < FR; r++)
        ws[X3o + (size_t)(row0 + r) * C + t] = (rv[r] - mv[r][0]) * mv[r][1];
}

// ---------------- masked view-mean + output0 ----------------
__global__ __launch_bounds__(256) void k_fuse(const int* maskin, float* ws, float* out) {
    int row = blockIdx.x, j = threadIdx.x;
    int b = row / P, p = row % P;
    float s = 0.f, cnt = 0.f;
    for (int v = 0; v < V; v++) {
        bool mk = (maskin[(b * P + p) * V + v] > 0) && (ws[MFLAG + b * V + v] > 0.5f);
        if (mk) {
            s += ws[X3o + ((size_t)((b * V + v) * P + p)) * C + j];
            cnt += 1.f;
        }
    }
    float f = s / (cnt + 1e-4f);
    ws[FUSEDo + (size_t)row * C + j] = f;
    out[O0 + ((size_t)b * C + j) * P + p] = f;
}

// ---------------- pred head + BEV outputs ----------------
__global__ __launch_bounds__(256) void k_pred(const float* w1, const float* b1, const float* w2, const float* b2,
                                              const float* qposin, float* ws, float* out) {
    int row = blockIdx.x, j = threadIdx.x;
    __shared__ __align__(16) float in[C];
    __shared__ float red[256];
    __shared__ float cen[4];
    in[j] = ws[FUSEDo + (size_t)row * C + j];
    __syncthreads();
    float h = fmaxf(b1[j] + dotK(in, w1, j, C, C), 0.f);
    for (int i = 0; i < 3; i++) {
        float s = blockReduceSum(h * w2[j * 3 + i], red);
        if (j == 0) cen[i] = s + b2[i] + qposin[row * 3 + i];
    }
    if (j == 0) {
        float c0 = cen[0], c1 = cen[1], c2 = cen[2];
        float cx = (c0 + 54.f) / 108.f * 135.f;
        float cy = (c1 + 54.f) / 108.f * 135.f;
        int b = row / P, p = row % P;
        out[O1 + (size_t)row * 3 + 0] = c0;
        out[O1 + (size_t)row * 3 + 1] = c1;
        out[O1 + (size_t)row * 3 + 2] = c2;
        out[O2 + (size_t)row * 2 + 0] = cx;
        out[O2 + (size_t)row * 2 + 1] = cy;
        out[O3 + (size_t)b * 2 * P + 0 * P + p] = cx;
        out[O3 + (size_t)b * 2 * P + 1 * P + p] = cy;
        out[O4 + (size_t)b * P + p] = c2;
    }
}

extern "C" void kernel_launch(void* const* d_in, const int* in_sizes, int n_in,
                              void* d_out, int out_size, void* d_ws, size_t ws_size,
                              hipStream_t stream) {
    const float* qfeat  = (const float*)d_in[0];
    const float* qposin = (const float*)d_in[1];
    const int*   maskin = (const int*)d_in[2];
    const float* feats  = (const float*)d_in[3];
    const float* npos   = (const float*)d_in[4];
    const float* rt     = (const float*)d_in[5];
    const float* l2cr   = (const float*)d_in[6];
    const float* l2ct   = (const float*)d_in[7];
    const float* qp_w1 = (const float*)d_in[8],  * qp_b1 = (const float*)d_in[9];
    const float* qp_w2 = (const float*)d_in[10], * qp_b2 = (const float*)d_in[11];
    const float* kp_w1 = (const float*)d_in[12], * kp_b1 = (const float*)d_in[13];
    const float* kp_w2 = (const float*)d_in[14], * kp_b2 = (const float*)d_in[15];
    const float* sa_wq = (const float*)d_in[16], * sa_wk = (const float*)d_in[17];
    const float* sa_wv = (const float*)d_in[18], * sa_wo = (const float*)d_in[19];
    const float* dv_w  = (const float*)d_in[20];
    const float* doffw = (const float*)d_in[21], * doffb = (const float*)d_in[22];
    const float* dattw = (const float*)d_in[23], * dattb = (const float*)d_in[24];
    const float* doutw = (const float*)d_in[25];
    const float* f_w1  = (const float*)d_in[26], * f_b1 = (const float*)d_in[27];
    const float* f_w2  = (const float*)d_in[28], * f_b2 = (const float*)d_in[29];
    const float* p_w1  = (const float*)d_in[30], * p_b1 = (const float*)d_in[31];
    const float* p_w2  = (const float*)d_in[32], * p_b2 = (const float*)d_in[33];

    float* ws = (float*)d_ws;
    bf16* vals = (bf16*)((char*)d_ws + VALS_BYTE_OFF);
    bf16* kw2T = vals + VALS_ELEMS;
    bf16* dvwT = kw2T + (size_t)C * C;
    float* out = (float*)d_out;

    k_setup<<<1, 64, 0, stream>>>(rt, l2cr, l2ct, maskin, ws);
    k_wprep<<<512, 256, 0, stream>>>(kp_w2, dv_w, kw2T, dvwT);
    k_qpos<<<BP, 256, 0, stream>>>(qfeat, qposin, qp_w1, qp_b1, qp_w2, qp_b2, ws);
    k_qkv<<<dim3(BP, 3), 256, 0, stream>>>(sa_wq, sa_wk, sa_wv, ws);
    k_logits<<<B * HH * P, 256, 0, stream>>>(ws);
    k_sattn<<<B * V * HH * P, 256, 0, stream>>>(maskin, ws);
    k_saout<<<BVP, 256, 0, stream>>>(sa_wo, ws);
    k_ref<<<(BVP + 255) / 256, 256, 0, stream>>>(qposin, rt, ws);
    k_offaw<<<BVP, 256, 0, stream>>>(doffw, doffb, dattw, dattb, ws);
    k_vals_mfma<<<dim3(NVT, BV), 256, 0, stream>>>(npos, feats, kp_w1, kp_b1, kp_b2, kw2T, dvwT, ws, vals);
    k_sample<<<BVP, 256, 0, stream>>>(ws, vals, ws);
    k_dout<<<BVP, 256, 0, stream>>>(doutw, ws);
    k_ffn<<<BVP / FR, 256, 0, stream>>>(f_w1, f_b1, f_w2, f_b2, ws);
    k_fuse<<<BP, 256, 0, stream>>>(maskin, ws, out);
    k_pred<<<BP, 256, 0, stream>>>(p_w1, p_b1, p_w2, p_b2, qposin, ws, out);
}

// Round 6
// 837.476 us; speedup vs baseline: 2.3781x; 1.2581x over previous
//
#include <hip/hip_runtime.h>
#include <hip/hip_bf16.h>
#include <cstdint>
#include <cstddef>

using bf16 = __hip_bfloat16;
#define DEVFN static __device__ __forceinline__

constexpr int B = 4, V = 6, P = 200, C = 256, HH = 8, Dh = 32, NLEV = 4, NPTS = 4, FFN = 1024;
constexpr int L = 7441;
constexpr int BV = B * V, BP = B * P, BVP = B * V * P, BVL = B * V * L;
constexpr float IMG_W = 800.f, IMG_H = 448.f;

__constant__ int cLH[4] = {56, 28, 14, 7};
__constant__ int cLW[4] = {100, 50, 25, 13};
__constant__ int cLS[4] = {0, 5600, 7000, 7350};

// ---- workspace layout (offsets in floats) ----
constexpr size_t IRT   = 0;
constexpr size_t CAMT  = IRT + (size_t)BV * 16;
constexpr size_t MFLAG = CAMT + (size_t)BV * 3;
constexpr size_t Xo    = MFLAG + BV;
constexpr size_t QPOSo = Xo + (size_t)BP * C;
constexpr size_t Qo    = QPOSo + (size_t)BP * C;
constexpr size_t Ko    = Qo + (size_t)BP * C;
constexpr size_t VVo   = Ko + (size_t)BP * C;
constexpr size_t LOGo  = VVo + (size_t)BP * C;
constexpr size_t SAo   = LOGo + (size_t)B * HH * P * P;
constexpr size_t X1o   = SAo + (size_t)BVP * C;
constexpr size_t REFo  = X1o + (size_t)BVP * C;
constexpr size_t OFFo  = REFo + (size_t)BVP * 2;
constexpr size_t AWo   = OFFo + (size_t)BVP * 256;
constexpr size_t OUTSo = AWo + (size_t)BVP * 128;
constexpr size_t X2o   = OUTSo + (size_t)BVP * C;
constexpr size_t X3o   = X2o + (size_t)BVP * C;
constexpr size_t FUSEDo= X3o + (size_t)BVP * C;
constexpr size_t WS_FLOATS = FUSEDo + (size_t)BP * C;
constexpr size_t VALS_BYTE_OFF = ((WS_FLOATS * 4 + 255) / 256) * 256;
constexpr size_t VALS_ELEMS = (size_t)BVL * C;   // bf16

// bf16 weight region (elements, after vals)
constexpr size_t KW2T_O  = 0;
constexpr size_t DVWT_O  = 65536;
constexpr size_t WOT_O   = 131072;
constexpr size_t DOUTT_O = 196608;
constexpr size_t OAWT_O  = 262144;            // 384x256
constexpr size_t QKVT_O  = 360448;            // 768x512
constexpr size_t W1T_O   = 753664;            // 1024x256
constexpr size_t W2T_O   = 1015808;           // 256x1024
constexpr size_t HIDB_O  = 1277952;           // 4800x1024 bf16

// ---- output layout (elements, f32) ----
constexpr size_t O0 = 0;
constexpr size_t O1 = O0 + (size_t)B * C * P;
constexpr size_t O2 = O1 + (size_t)B * P * 3;
constexpr size_t O3 = O2 + (size_t)B * P * 2;
constexpr size_t O4 = O3 + (size_t)B * 2 * P;

DEVFN float tof(bf16 x) { return __bfloat162float(x); }
DEVFN bf16  tobf(float x) { return __float2bfloat16(x); }

typedef __attribute__((ext_vector_type(8))) short short8;
typedef __attribute__((ext_vector_type(4))) float floatx4;

DEVFN float blockReduceSum(float v, float* red) {
    int j = threadIdx.x;
    __syncthreads();
    red[j] = v; __syncthreads();
    for (int s = 128; s > 0; s >>= 1) { if (j < s) red[j] += red[j + s]; __syncthreads(); }
    return red[0];
}
DEVFN float blockReduceMax(float v, float* red) {
    int j = threadIdx.x;
    __syncthreads();
    red[j] = v; __syncthreads();
    for (int s = 128; s > 0; s >>= 1) { if (j < s) red[j] = fmaxf(red[j], red[j + s]); __syncthreads(); }
    return red[0];
}

DEVFN float dotK(const float* __restrict__ s, const float* __restrict__ W, int j, int N, int K) {
    float acc = 0.f;
    for (int k = 0; k < K; k += 4) {
        float4 h = *(const float4*)(s + k);
        acc += h.x * W[(size_t)(k + 0) * N + j];
        acc += h.y * W[(size_t)(k + 1) * N + j];
        acc += h.z * W[(size_t)(k + 2) * N + j];
        acc += h.w * W[(size_t)(k + 3) * N + j];
    }
    return acc;
}

// ---------------- setup ----------------
__global__ __launch_bounds__(64) void k_setup(const float* rt, const float* l2cr, const float* l2ct,
                                              const int* maskin, float* ws) {
    int t = threadIdx.x;
    if (t >= BV) return;
    float m[16], inv[16];
    for (int i = 0; i < 16; i++) m[i] = rt[t * 16 + i];
    inv[0]  =  m[5]*m[10]*m[15] - m[5]*m[11]*m[14] - m[9]*m[6]*m[15] + m[9]*m[7]*m[14] + m[13]*m[6]*m[11] - m[13]*m[7]*m[10];
    inv[4]  = -m[4]*m[10]*m[15] + m[4]*m[11]*m[14] + m[8]*m[6]*m[15] - m[8]*m[7]*m[14] - m[12]*m[6]*m[11] + m[12]*m[7]*m[10];
    inv[8]  =  m[4]*m[9]*m[15]  - m[4]*m[11]*m[13] - m[8]*m[5]*m[15] + m[8]*m[7]*m[13] + m[12]*m[5]*m[11] - m[12]*m[7]*m[9];
    inv[12] = -m[4]*m[9]*m[14]  + m[4]*m[10]*m[13] + m[8]*m[5]*m[14] - m[8]*m[6]*m[13] - m[12]*m[5]*m[10] + m[12]*m[6]*m[9];
    inv[1]  = -m[1]*m[10]*m[15] + m[1]*m[11]*m[14] + m[9]*m[2]*m[15] - m[9]*m[3]*m[14] - m[13]*m[2]*m[11] + m[13]*m[3]*m[10];
    inv[5]  =  m[0]*m[10]*m[15] - m[0]*m[11]*m[14] - m[8]*m[2]*m[15] + m[8]*m[3]*m[14] + m[12]*m[2]*m[11] - m[12]*m[3]*m[10];
    inv[9]  = -m[0]*m[9]*m[15]  + m[0]*m[11]*m[13] + m[8]*m[1]*m[15] - m[8]*m[3]*m[13] - m[12]*m[1]*m[11] + m[12]*m[3]*m[9];
    inv[13] =  m[0]*m[9]*m[14]  - m[0]*m[10]*m[13] - m[8]*m[1]*m[14] + m[8]*m[2]*m[13] + m[12]*m[1]*m[10] - m[12]*m[2]*m[9];
    inv[2]  =  m[1]*m[6]*m[15]  - m[1]*m[7]*m[14]  - m[5]*m[2]*m[15] + m[5]*m[3]*m[14] + m[13]*m[2]*m[7]  - m[13]*m[3]*m[6];
    inv[6]  = -m[0]*m[6]*m[15]  + m[0]*m[7]*m[14]  + m[4]*m[2]*m[15] - m[4]*m[3]*m[14] - m[12]*m[2]*m[7]  + m[12]*m[3]*m[6];
    inv[10] =  m[0]*m[5]*m[15]  - m[0]*m[7]*m[13]  - m[4]*m[1]*m[15] + m[4]*m[3]*m[13] + m[12]*m[1]*m[7]  - m[12]*m[3]*m[5];
    inv[14] = -m[0]*m[5]*m[14]  + m[0]*m[6]*m[13]  + m[4]*m[1]*m[14] - m[4]*m[2]*m[13] - m[12]*m[1]*m[6]  + m[12]*m[2]*m[5];
    inv[3]  = -m[1]*m[6]*m[11]  + m[1]*m[7]*m[10]  + m[5]*m[2]*m[11] - m[5]*m[3]*m[10] - m[9]*m[2]*m[7]   + m[9]*m[3]*m[6];
    inv[7]  =  m[0]*m[6]*m[11]  - m[0]*m[7]*m[10]  - m[4]*m[2]*m[11] + m[4]*m[3]*m[10] + m[8]*m[2]*m[7]   - m[8]*m[3]*m[6];
    inv[11] = -m[0]*m[5]*m[11]  + m[0]*m[7]*m[9]   + m[4]*m[1]*m[11] - m[4]*m[3]*m[9]  - m[8]*m[1]*m[7]   + m[8]*m[3]*m[5];
    inv[15] =  m[0]*m[5]*m[10]  - m[0]*m[6]*m[9]   - m[4]*m[1]*m[10] + m[4]*m[2]*m[9]  + m[8]*m[1]*m[6]   - m[8]*m[2]*m[5];
    float det = m[0]*inv[0] + m[1]*inv[4] + m[2]*inv[8] + m[3]*inv[12];
    float rd = 1.f / det;
    for (int i = 0; i < 16; i++) ws[IRT + t * 16 + i] = inv[i] * rd;
    float r9[9], tv[3];
    for (int i = 0; i < 9; i++) r9[i] = l2cr[t * 9 + i];
    for (int i = 0; i < 3; i++) tv[i] = l2ct[t * 3 + i];
    for (int i = 0; i < 3; i++)
        ws[CAMT + t * 3 + i] = -(r9[0 * 3 + i] * tv[0] + r9[1 * 3 + i] * tv[1] + r9[2 * 3 + i] * tv[2]);
    int b = t / V, v = t % V, cnt = 0;
    for (int p = 0; p < P; p++) cnt += (maskin[(b * P + p) * V + v] > 0) ? 1 : 0;
    ws[MFLAG + t] = (cnt > 1) ? 1.f : 0.f;
}

// ---------------- weight prep: all bf16 [N][K] transposes ----------------
__global__ __launch_bounds__(256) void k_wprep_all(
        const float* kw2, const float* dvw, const float* wo, const float* dw,
        const float* offw, const float* attw, const float* wq, const float* wk, const float* wv,
        const float* w1, const float* w2, bf16* wb) {
    int bid = blockIdx.x, t = threadIdx.x;
    if (bid < 1024) {           // four 256x256 transposes
        int reg = bid >> 8, n = bid & 255;
        const float* src = (reg == 0) ? kw2 : (reg == 1) ? dvw : (reg == 2) ? wo : dw;
        wb[(size_t)reg * 65536 + (size_t)n * 256 + t] = tobf(src[(size_t)t * 256 + n]);
    } else if (bid < 1408) {    // oawT: 384 rows
        int n = bid - 1024;
        float v = (n < 256) ? offw[(size_t)t * 256 + n] : attw[(size_t)t * 128 + (n - 256)];
        wb[OAWT_O + (size_t)n * 256 + t] = tobf(v);
    } else if (bid < 2176) {    // qkvT: 768 rows, K=512
        int n = bid - 1408;
        bf16* dst = wb + QKVT_O + (size_t)n * 512;
        float v0 = (n < 256) ? wq[(size_t)t * 256 + n] : (n < 512) ? wk[(size_t)t * 256 + (n - 256)]
                                                                   : wv[(size_t)t * 256 + (n - 512)];
        dst[t] = tobf(v0);
        float v1 = (n < 256) ? wq[(size_t)t * 256 + n] : (n < 512) ? wk[(size_t)t * 256 + (n - 256)] : 0.f;
        dst[t + 256] = tobf(v1);
    } else if (bid < 3200) {    // w1T: 1024 rows, K=256
        int n = bid - 2176;
        wb[W1T_O + (size_t)n * 256 + t] = tobf(w1[(size_t)t * 1024 + n]);
    } else {                    // w2T: 256 rows, K=1024
        int n = bid - 3200;
        bf16* dst = wb + W2T_O + (size_t)n * 1024;
        for (int kk = 0; kk < 4; kk++)
            dst[t + kk * 256] = tobf(w2[(size_t)(t + kk * 256) * 256 + n]);
    }
}

// ---------------- qpos MLP + x transpose ----------------
__global__ __launch_bounds__(256) void k_qpos(const float* qfeat, const float* qposin,
                                              const float* w1, const float* b1, const float* w2, const float* b2,
                                              float* ws) {
    int row = blockIdx.x, j = threadIdx.x;
    int b = row / P, p = row % P;
    __shared__ __align__(16) float pos[4];
    __shared__ __align__(16) float hid[C];
    if (j < 3) pos[j] = qposin[row * 3 + j];
    __syncthreads();
    float h = b1[j] + pos[0] * w1[0 * C + j] + pos[1] * w1[1 * C + j] + pos[2] * w1[2 * C + j];
    hid[j] = fmaxf(h, 0.f);
    __syncthreads();
    float acc = b2[j] + dotK(hid, w2, j, C, C);
    ws[QPOSo + (size_t)row * C + j] = acc;
    ws[Xo + (size_t)row * C + j] = qfeat[((size_t)b * C + j) * P + p];
}

// ---------------- qkv via one MFMA GEMM: [x|qpos](800x512) @ B'(512x768) ----------------
constexpr int AST2 = 520;   // bf16, 1040 B rows (65*16)
__global__ __launch_bounds__(256) void k_qkv_mfma(const bf16* __restrict__ qkvT, float* ws) {
    __shared__ __align__(16) bf16 As[16 * AST2];
    int row0 = blockIdx.x * 16;
    int t = threadIdx.x;
    for (int rr = 0; rr < 16; rr++) {
        As[rr * AST2 + t]       = tobf(ws[Xo + (size_t)(row0 + rr) * C + t]);
        As[rr * AST2 + 256 + t] = tobf(ws[QPOSo + (size_t)(row0 + rr) * C + t]);
    }
    __syncthreads();
    int wave = t >> 6, lane = t & 63, quad = lane >> 4, l15 = lane & 15;
    int n0 = wave * 192;
    floatx4 acc[12];
    #pragma unroll
    for (int nt = 0; nt < 12; nt++) acc[nt] = (floatx4){0.f, 0.f, 0.f, 0.f};
    for (int kk = 0; kk < 16; kk++) {
        short8 a = *(const short8*)&As[l15 * AST2 + kk * 32 + quad * 8];
        #pragma unroll
        for (int nt = 0; nt < 12; nt++) {
            short8 bf = *(const short8*)&qkvT[(size_t)(n0 + nt * 16 + l15) * 512 + kk * 32 + quad * 8];
            acc[nt] = __builtin_amdgcn_mfma_f32_16x16x32_bf16(a, bf, acc[nt], 0, 0, 0);
        }
    }
    #pragma unroll
    for (int nt = 0; nt < 12; nt++) {
        int n = n0 + nt * 16 + l15;
        int which = n >> 8, c = n & 255;
        size_t dst = (which == 0) ? Qo : (which == 1) ? Ko : VVo;
        int row = row0 + quad * 4;
        #pragma unroll
        for (int u = 0; u < 4; u++)
            ws[dst + (size_t)(row + u) * C + c] = acc[nt][u];
    }
}

// ---------------- attention logits ----------------
__global__ __launch_bounds__(256) void k_logits(float* ws) {
    int bid = blockIdx.x;
    int qi = bid % P, h = (bid / P) % HH, b = bid / (P * HH);
    int j = threadIdx.x;
    __shared__ __align__(16) float qf[Dh];
    if (j < Dh) qf[j] = ws[Qo + ((size_t)(b * P + qi)) * C + h * Dh + j];
    __syncthreads();
    if (j < P) {
        const float* kp = ws + Ko + ((size_t)(b * P + j)) * C + h * Dh;
        float acc = 0.f;
        for (int d = 0; d < Dh; d += 4) {
            float4 kv = *(const float4*)(kp + d);
            float4 qv = *(const float4*)(qf + d);
            acc += kv.x * qv.x + kv.y * qv.y + kv.z * qv.z + kv.w * qv.w;
        }
        ws[LOGo + (size_t)bid * P + j] = acc * 0.17677669529663687f;
    }
}

// ---------------- masked softmax + attn @ V ----------------
__global__ __launch_bounds__(256) void k_sattn(const int* maskin, float* ws) {
    int bid = blockIdx.x;
    int qi = bid % P, h = (bid / P) % HH, v = (bid / (P * HH)) % V, b = bid / (P * HH * V);
    int j = threadIdx.x;
    __shared__ float attn[256];
    __shared__ float red[256];
    float flag = ws[MFLAG + b * V + v];
    float val = -1e30f;
    if (j < P) {
        float lg = ws[LOGo + ((size_t)(b * HH + h) * P + qi) * P + j];
        bool mk = (flag > 0.5f) && (maskin[(b * P + j) * V + v] > 0);
        val = lg + (mk ? 0.f : -1e9f);
    }
    float mx = blockReduceMax(val, red);
    float e = (j < P) ? __expf(val - mx) : 0.f;
    float s = blockReduceSum(e, red);
    attn[j] = e / s;
    __syncthreads();
    int d = j & 31, c = j >> 5;
    const float* vvp = ws + VVo + (size_t)b * P * C + h * Dh + d;
    float acc = 0.f;
    for (int kk = c * 25; kk < c * 25 + 25; ++kk) acc += attn[kk] * vvp[(size_t)kk * C];
    red[j] = acc; __syncthreads();
    if (j < Dh) {
        float s2 = 0.f;
        for (int c2 = 0; c2 < 8; c2++) s2 += red[c2 * 32 + j];
        ws[SAo + ((size_t)((b * V + v) * P + qi)) * C + h * Dh + j] = s2;
    }
}

// ---------------- generic MFMA row-GEMM (K=256,N=256) + residual + LN ----------------
constexpr int GAST = 264;   // bf16 A stride
constexpr int OST = 260;    // f32 out stride
__global__ __launch_bounds__(256) void k_lngemm(const bf16* __restrict__ WT,
        float* ws, size_t aOff, size_t residOff, int residMode, size_t dstOff) {
    __shared__ __align__(16) bf16 As[32 * GAST];
    __shared__ __align__(16) float Os[32 * OST];
    __shared__ float redw[4][8][2];
    __shared__ float mv[8][2];
    int row0 = blockIdx.x * 32;
    int t = threadIdx.x;
    for (int rr = 0; rr < 32; rr++)
        As[rr * GAST + t] = tobf(ws[aOff + (size_t)(row0 + rr) * C + t]);
    __syncthreads();
    int wave = t >> 6, lane = t & 63, quad = lane >> 4, l15 = lane & 15;
    int n0 = wave * 64;
    floatx4 acc[2][4];
    #pragma unroll
    for (int i = 0; i < 2; i++)
        #pragma unroll
        for (int nt = 0; nt < 4; nt++) acc[i][nt] = (floatx4){0.f, 0.f, 0.f, 0.f};
    for (int kk = 0; kk < 8; kk++) {
        short8 a0 = *(const short8*)&As[l15 * GAST + kk * 32 + quad * 8];
        short8 a1 = *(const short8*)&As[(16 + l15) * GAST + kk * 32 + quad * 8];
        #pragma unroll
        for (int nt = 0; nt < 4; nt++) {
            short8 bf = *(const short8*)&WT[(size_t)(n0 + nt * 16 + l15) * 256 + kk * 32 + quad * 8];
            acc[0][nt] = __builtin_amdgcn_mfma_f32_16x16x32_bf16(a0, bf, acc[0][nt], 0, 0, 0);
            acc[1][nt] = __builtin_amdgcn_mfma_f32_16x16x32_bf16(a1, bf, acc[1][nt], 0, 0, 0);
        }
    }
    #pragma unroll
    for (int i = 0; i < 2; i++)
        #pragma unroll
        for (int nt = 0; nt < 4; nt++) {
            int col = n0 + nt * 16 + l15;
            int rl = i * 16 + quad * 4;
            #pragma unroll
            for (int u = 0; u < 4; u++) Os[(rl + u) * OST + col] = acc[i][nt][u];
        }
    __syncthreads();
    int lane2 = t & 63, wv = t >> 6;
    for (int g = 0; g < 4; g++) {
        float rv[8];
        #pragma unroll
        for (int r = 0; r < 8; r++) {
            int grow = row0 + g * 8 + r;
            int ridx = residMode ? ((grow / (P * V)) * P + grow % P) : grow;
            rv[r] = Os[(g * 8 + r) * OST + t] + ws[residOff + (size_t)ridx * C + t];
        }
        #pragma unroll
        for (int r = 0; r < 8; r++) {
            float s = rv[r], q = rv[r] * rv[r];
            for (int off = 32; off > 0; off >>= 1) {
                s += __shfl_down(s, off, 64);
                q += __shfl_down(q, off, 64);
            }
            if (lane2 == 0) { redw[wv][r][0] = s; redw[wv][r][1] = q; }
        }
        __syncthreads();
        if (t < 8) {
            float s = redw[0][t][0] + redw[1][t][0] + redw[2][t][0] + redw[3][t][0];
            float q = redw[0][t][1] + redw[1][t][1] + redw[2][t][1] + redw[3][t][1];
            float mean = s * (1.f / C);
            float var = q * (1.f / C) - mean * mean;
            mv[t][0] = mean; mv[t][1] = rsqrtf(var + 1e-5f);
        }
        __syncthreads();
        #pragma unroll
        for (int r = 0; r < 8; r++) {
            int grow = row0 + g * 8 + r;
            ws[dstOff + (size_t)grow * C + t] = (rv[r] - mv[r][0]) * mv[r][1];
        }
        __syncthreads();
    }
}

// ---------------- reference points ----------------
__global__ __launch_bounds__(256) void k_ref(const float* qposin, const float* rt, float* ws) {
    int tid = blockIdx.x * 256 + threadIdx.x;
    if (tid >= BVP) return;
    int p = tid % P, v = (tid / P) % V, b = tid / (P * V);
    float p0 = qposin[(b * P + p) * 3 + 0];
    float p1 = qposin[(b * P + p) * 3 + 1];
    float p2 = qposin[(b * P + p) * 3 + 2];
    const float* m = rt + (size_t)(b * V + v) * 16;
    float pr[3];
    for (int i = 0; i < 3; i++)
        pr[i] = m[i * 4 + 0] * p0 + m[i * 4 + 1] * p1 + m[i * 4 + 2] * p2 + m[i * 4 + 3];
    ws[REFo + (size_t)tid * 2 + 0] = pr[0] / pr[2] / IMG_W;
    ws[REFo + (size_t)tid * 2 + 1] = pr[1] / pr[2] / IMG_H;
}

// ---------------- off + aw heads via MFMA (N=384) ----------------
constexpr int OAWST = 392;
__global__ __launch_bounds__(256) void k_offaw_mfma(const bf16* __restrict__ oawT,
        const float* __restrict__ ob, const float* __restrict__ ab, float* ws) {
    __shared__ __align__(16) bf16 As[32 * GAST];
    __shared__ __align__(16) float Os[32 * OAWST];
    int row0 = blockIdx.x * 32;
    int t = threadIdx.x;
    for (int rr = 0; rr < 32; rr++) {
        int grow = row0 + rr;
        int ridx = (grow / (P * V)) * P + grow % P;
        As[rr * GAST + t] = tobf(ws[X1o + (size_t)grow * C + t] + ws[QPOSo + (size_t)ridx * C + t]);
    }
    __syncthreads();
    int wave = t >> 6, lane = t & 63, quad = lane >> 4, l15 = lane & 15;
    int n0 = wave * 96;
    floatx4 acc[2][6];
    #pragma unroll
    for (int i = 0; i < 2; i++)
        #pragma unroll
        for (int nt = 0; nt < 6; nt++) acc[i][nt] = (floatx4){0.f, 0.f, 0.f, 0.f};
    for (int kk = 0; kk < 8; kk++) {
        short8 a0 = *(const short8*)&As[l15 * GAST + kk * 32 + quad * 8];
        short8 a1 = *(const short8*)&As[(16 + l15) * GAST + kk * 32 + quad * 8];
        #pragma unroll
        for (int nt = 0; nt < 6; nt++) {
            short8 bf = *(const short8*)&oawT[(size_t)(n0 + nt * 16 + l15) * 256 + kk * 32 + quad * 8];
            acc[0][nt] = __builtin_amdgcn_mfma_f32_16x16x32_bf16(a0, bf, acc[0][nt], 0, 0, 0);
            acc[1][nt] = __builtin_amdgcn_mfma_f32_16x16x32_bf16(a1, bf, acc[1][nt], 0, 0, 0);
        }
    }
    #pragma unroll
    for (int i = 0; i < 2; i++)
        #pragma unroll
        for (int nt = 0; nt < 6; nt++) {
            int col = n0 + nt * 16 + l15;
            int rl = i * 16 + quad * 4;
            #pragma unroll
            for (int u = 0; u < 4; u++) Os[(rl + u) * OAWST + col] = acc[i][nt][u];
        }
    __syncthreads();
    // off: col t, 32 rows
    float obv = ob[t];
    for (int r = 0; r < 32; r++)
        ws[OFFo + (size_t)(row0 + r) * 256 + t] = Os[r * OAWST + t] + obv;
    // aw softmax-16: thread t -> (row r = t>>3, group g = t&7)
    {
        int r = t >> 3, g = t & 7;
        const float* lg = &Os[r * OAWST + 256 + g * 16];
        float mx = -1e30f;
        #pragma unroll
        for (int i = 0; i < 16; i++) mx = fmaxf(mx, lg[i] + ab[g * 16 + i]);
        float s = 0.f;
        float ex[16];
        #pragma unroll
        for (int i = 0; i < 16; i++) { ex[i] = __expf(lg[i] + ab[g * 16 + i] - mx); s += ex[i]; }
        float rs = 1.f / s;
        #pragma unroll
        for (int i = 0; i < 16; i++)
            ws[AWo + (size_t)(row0 + r) * 128 + g * 16 + i] = ex[i] * rs;
    }
}

// ---------------- vals via MFMA (unchanged from round 5) ----------------
constexpr int VROWS = 64;
constexpr int ASTR = C + 8;
constexpr int NVT = (L + VROWS - 1) / VROWS;

__global__ __launch_bounds__(256, 4) void k_vals_mfma(
        const float* __restrict__ npos, const float* __restrict__ feats,
        const float* __restrict__ kw1, const float* __restrict__ kb1, const float* __restrict__ kb2,
        const bf16* __restrict__ kw2T, const bf16* __restrict__ dvwT,
        const float* __restrict__ ws, bf16* __restrict__ vals) {
    __shared__ __align__(16) bf16 As[VROWS * ASTR];
    __shared__ float kp6s[VROWS][8];
    __shared__ float kb2s[C];
    int bv = blockIdx.y;
    int l0 = blockIdx.x * VROWS;
    int t = threadIdx.x;
    kb2s[t] = kb2[t];
    if (t < VROWS) {
        int l = min(l0 + t, L - 1);
        float sx = 1.f / (1.f + __expf(-npos[l * 2 + 0])) * IMG_W;
        float sy = 1.f / (1.f + __expf(-npos[l * 2 + 1])) * IMG_H;
        const float* inv = ws + IRT + (size_t)bv * 16;
        #pragma unroll
        for (int i = 0; i < 3; i++)
            kp6s[t][i] = inv[i * 4 + 0] * sx + inv[i * 4 + 1] * sy + inv[i * 4 + 2] + inv[i * 4 + 3];
        #pragma unroll
        for (int i = 0; i < 3; i++) kp6s[t][3 + i] = ws[CAMT + (size_t)bv * 3 + i];
    }
    __syncthreads();
    {
        float w1j[6];
        #pragma unroll
        for (int i = 0; i < 6; i++) w1j[i] = kw1[i * C + t];
        float bb = kb1[t];
        for (int r = 0; r < VROWS; r++) {
            float h = bb;
            #pragma unroll
            for (int i = 0; i < 6; i++) h += kp6s[r][i] * w1j[i];
            As[r * ASTR + t] = tobf(fmaxf(h, 0.f));
        }
    }
    __syncthreads();
    int wave = t >> 6, lane = t & 63;
    int quad = lane >> 4, l15 = lane & 15;
    int mh = (wave >> 1) * 32;
    int nh = (wave & 1) * 128;
    floatx4 acc[2][8];
    #pragma unroll
    for (int i = 0; i < 2; i++)
        #pragma unroll
        for (int nt = 0; nt < 8; nt++) acc[i][nt] = (floatx4){0.f, 0.f, 0.f, 0.f};
    for (int kk = 0; kk < 8; kk++) {
        short8 a0 = *(const short8*)&As[(mh + l15) * ASTR + kk * 32 + quad * 8];
        short8 a1 = *(const short8*)&As[(mh + 16 + l15) * ASTR + kk * 32 + quad * 8];
        #pragma unroll
        for (int nt = 0; nt < 8; nt++) {
            short8 bfr = *(const short8*)&kw2T[(size_t)(nh + nt * 16 + l15) * C + kk * 32 + quad * 8];
            acc[0][nt] = __builtin_amdgcn_mfma_f32_16x16x32_bf16(a0, bfr, acc[0][nt], 0, 0, 0);
            acc[1][nt] = __builtin_amdgcn_mfma_f32_16x16x32_bf16(a1, bfr, acc[1][nt], 0, 0, 0);
        }
    }
    __syncthreads();
    #pragma unroll
    for (int i = 0; i < 2; i++) {
        #pragma unroll
        for (int nt = 0; nt < 8; nt++) {
            int c = nh + nt * 16 + l15;
            int rb = mh + i * 16 + quad * 4;
            #pragma unroll
            for (int u = 0; u < 4; u++)
                As[(rb + u) * ASTR + c] = tobf(acc[i][nt][u]);
        }
    }
    __syncthreads();
    if (l0 + VROWS <= L) {
        #pragma unroll
        for (int round = 0; round < 16; round++) {
            int q = round * 256 + t;
            int c = q >> 4, ql = (q & 15) * 4;
            float4 f = *(const float4*)&feats[((size_t)bv * C + c) * L + l0 + ql];
            float bias = kb2s[c];
            int a0i = ql * ASTR + c;
            As[a0i]            = tobf(tof(As[a0i])            + bias + f.x);
            As[a0i + ASTR]     = tobf(tof(As[a0i + ASTR])     + bias + f.y);
            As[a0i + 2 * ASTR] = tobf(tof(As[a0i + 2 * ASTR]) + bias + f.z);
            As[a0i + 3 * ASTR] = tobf(tof(As[a0i + 3 * ASTR]) + bias + f.w);
        }
    } else {
        for (int round = 0; round < 16; round++) {
            int q = round * 256 + t;
            int c = q >> 4, ql = (q & 15) * 4;
            float bias = kb2s[c];
            #pragma unroll
            for (int u = 0; u < 4; u++) {
                int l = l0 + ql + u;
                if (l < L) {
                    int ai = (ql + u) * ASTR + c;
                    As[ai] = tobf(tof(As[ai]) + bias + feats[((size_t)bv * C + c) * L + l]);
                }
            }
        }
    }
    __syncthreads();
    #pragma unroll
    for (int i = 0; i < 2; i++)
        #pragma unroll
        for (int nt = 0; nt < 8; nt++) acc[i][nt] = (floatx4){0.f, 0.f, 0.f, 0.f};
    for (int kk = 0; kk < 8; kk++) {
        short8 a0 = *(const short8*)&As[(mh + l15) * ASTR + kk * 32 + quad * 8];
        short8 a1 = *(const short8*)&As[(mh + 16 + l15) * ASTR + kk * 32 + quad * 8];
        #pragma unroll
        for (int nt = 0; nt < 8; nt++) {
            short8 bfr = *(const short8*)&dvwT[(size_t)(nh + nt * 16 + l15) * C + kk * 32 + quad * 8];
            acc[0][nt] = __builtin_amdgcn_mfma_f32_16x16x32_bf16(a0, bfr, acc[0][nt], 0, 0, 0);
            acc[1][nt] = __builtin_amdgcn_mfma_f32_16x16x32_bf16(a1, bfr, acc[1][nt], 0, 0, 0);
        }
    }
    __syncthreads();
    #pragma unroll
    for (int i = 0; i < 2; i++) {
        #pragma unroll
        for (int nt = 0; nt < 8; nt++) {
            int c = nh + nt * 16 + l15;
            int rb = mh + i * 16 + quad * 4;
            #pragma unroll
            for (int u = 0; u < 4; u++)
                As[(rb + u) * ASTR + c] = tobf(acc[i][nt][u]);
        }
    }
    __syncthreads();
    #pragma unroll
    for (int pass = 0; pass < 8; pass++) {
        int row = pass * 8 + (t >> 5);
        int col = (t & 31) * 8;
        int l = l0 + row;
        if (l < L)
            *(int4*)&vals[((size_t)bv * L + l) * C + col] = *(const int4*)&As[row * ASTR + col];
    }
}

// ---------------- deformable bilinear sampling ----------------
__global__ __launch_bounds__(256) void k_sample(const float* ws, const bf16* vals, float* wsmut) {
    int row = blockIdx.x, j = threadIdx.x;
    int h = j >> 5, d = j & 31;
    __shared__ float soff[256];
    __shared__ float sawL[128];
    __shared__ float sref[2];
    soff[j] = ws[OFFo + (size_t)row * 256 + j];
    if (j < 128) sawL[j] = ws[AWo + (size_t)row * 128 + j];
    if (j < 2) sref[j] = ws[REFo + (size_t)row * 2 + j];
    __syncthreads();
    int v = (row / P) % V, b = row / (P * V);
    const bf16* vbase = vals + (size_t)(b * V + v) * L * C + h * Dh + d;
    float acc = 0.f;
    for (int l = 0; l < NLEV; l++) {
        float Wf = (float)cLW[l], Hf = (float)cLH[l];
        int Wi = cLW[l], Hi = cLH[l], S0 = cLS[l];
        for (int n = 0; n < NPTS; n++) {
            int oi = ((h * NLEV + l) * NPTS + n) * 2;
            float lx = sref[0] + soff[oi + 0] / Wf;
            float ly = sref[1] + soff[oi + 1] / Hf;
            float aww = sawL[(h * NLEV + l) * NPTS + n];
            float x = lx * Wf - 0.5f, y = ly * Hf - 0.5f;
            float x0f = floorf(x), y0f = floorf(y);
            float wx = x - x0f, wy = y - y0f;
            int x0 = (int)x0f, y0 = (int)y0f;
            float s = 0.f;
            #pragma unroll
            for (int dy = 0; dy < 2; dy++) {
                #pragma unroll
                for (int dx = 0; dx < 2; dx++) {
                    int xi = x0 + dx, yi = y0 + dy;
                    if (xi >= 0 && xi < Wi && yi >= 0 && yi < Hi) {
                        float wwt = (dx ? wx : 1.f - wx) * (dy ? wy : 1.f - wy);
                        s += wwt * tof(vbase[(size_t)(S0 + yi * Wi + xi) * C]);
                    }
                }
            }
            acc += aww * s;
        }
    }
    wsmut[OUTSo + (size_t)row * C + j] = acc;
}

// ---------------- FFN stage 1: x2 @ w1 + b1, relu -> hidb (bf16) ----------------
__global__ __launch_bounds__(256) void k_ffn1(const bf16* __restrict__ w1T, const float* __restrict__ b1,
                                              float* ws, bf16* hidb) {
    __shared__ __align__(16) bf16 As[32 * GAST];
    __shared__ __align__(16) bf16 Hs[32 * AST2];
    int row0 = blockIdx.x * 32;
    int nb = blockIdx.y * 512;
    int t = threadIdx.x;
    for (int rr = 0; rr < 32; rr++)
        As[rr * GAST + t] = tobf(ws[X2o + (size_t)(row0 + rr) * C + t]);
    __syncthreads();
    int wave = t >> 6, lane = t & 63, quad = lane >> 4, l15 = lane & 15;
    int n0 = wave * 128;
    floatx4 acc[2][8];
    #pragma unroll
    for (int i = 0; i < 2; i++)
        #pragma unroll
        for (int nt = 0; nt < 8; nt++) acc[i][nt] = (floatx4){0.f, 0.f, 0.f, 0.f};
    for (int kk = 0; kk < 8; kk++) {
        short8 a0 = *(const short8*)&As[l15 * GAST + kk * 32 + quad * 8];
        short8 a1 = *(const short8*)&As[(16 + l15) * GAST + kk * 32 + quad * 8];
        #pragma unroll
        for (int nt = 0; nt < 8; nt++) {
            short8 bf = *(const short8*)&w1T[(size_t)(nb + n0 + nt * 16 + l15) * 256 + kk * 32 + quad * 8];
            acc[0][nt] = __builtin_amdgcn_mfma_f32_16x16x32_bf16(a0, bf, acc[0][nt], 0, 0, 0);
            acc[1][nt] = __builtin_amdgcn_mfma_f32_16x16x32_bf16(a1, bf, acc[1][nt], 0, 0, 0);
        }
    }
    #pragma unroll
    for (int i = 0; i < 2; i++)
        #pragma unroll
        for (int nt = 0; nt < 8; nt++) {
            int cl = n0 + nt * 16 + l15;
            float bias = b1[nb + cl];
            int rl = i * 16 + quad * 4;
            #pragma unroll
            for (int u = 0; u < 4; u++)
                Hs[(rl + u) * AST2 + cl] = tobf(fmaxf(acc[i][nt][u] + bias, 0.f));
        }
    __syncthreads();
    #pragma unroll
    for (int pass = 0; pass < 8; pass++) {
        int row = pass * 4 + (t >> 6);
        int col = (t & 63) * 8;
        *(int4*)&hidb[(size_t)(row0 + row) * FFN + nb + col] = *(const int4*)&Hs[row * AST2 + col];
    }
}

// ---------------- FFN stage 2: hidb @ w2 + b2 + x2, LN -> x3 ----------------
__global__ __launch_bounds__(256) void k_ffn2(const bf16* __restrict__ w2T, const float* __restrict__ b2,
                                              const bf16* __restrict__ hidb, float* ws) {
    __shared__ __align__(16) float Os[32 * OST];
    __shared__ float redw[4][8][2];
    __shared__ float mv[8][2];
    int row0 = blockIdx.x * 32;
    int t = threadIdx.x;
    int wave = t >> 6, lane = t & 63, quad = lane >> 4, l15 = lane & 15;
    int n0 = wave * 64;
    floatx4 acc[2][4];
    #pragma unroll
    for (int i = 0; i < 2; i++)
        #pragma unroll
        for (int nt = 0; nt < 4; nt++) acc[i][nt] = (floatx4){0.f, 0.f, 0.f, 0.f};
    for (int kk = 0; kk < 32; kk++) {
        short8 a0 = *(const short8*)&hidb[(size_t)(row0 + l15) * FFN + kk * 32 + quad * 8];
        short8 a1 = *(const short8*)&hidb[(size_t)(row0 + 16 + l15) * FFN + kk * 32 + quad * 8];
        #pragma unroll
        for (int nt = 0; nt < 4; nt++) {
            short8 bf = *(const short8*)&w2T[(size_t)(n0 + nt * 16 + l15) * FFN + kk * 32 + quad * 8];
            acc[0][nt] = __builtin_amdgcn_mfma_f32_16x16x32_bf16(a0, bf, acc[0][nt], 0, 0, 0);
            acc[1][nt] = __builtin_amdgcn_mfma_f32_16x16x32_bf16(a1, bf, acc[1][nt], 0, 0, 0);
        }
    }
    #pragma unroll
    for (int i = 0; i < 2; i++)
        #pragma unroll
        for (int nt = 0; nt < 4; nt++) {
            int col = n0 + nt * 16 + l15;
            float bias = b2[col];
            int rl = i * 16 + quad * 4;
            #pragma unroll
            for (int u = 0; u < 4; u++) Os[(rl + u) * OST + col] = acc[i][nt][u] + bias;
        }
    __syncthreads();
    for (int g = 0; g < 4; g++) {
        float rv[8];
        #pragma unroll
        for (int r = 0; r < 8; r++) {
            int grow = row0 + g * 8 + r;
            rv[r] = Os[(g * 8 + r) * OST + t] + ws[X2o + (size_t)grow * C + t];
        }
        #pragma unroll
        for (int r = 0; r < 8; r++) {
            float s = rv[r], q = rv[r] * rv[r];
            for (int off = 32; off > 0; off >>= 1) {
                s += __shfl_down(s, off, 64);
                q += __shfl_down(q, off, 64);
            }
            if (lane == 0) { redw[wave][r][0] = s; redw[wave][r][1] = q; }
        }
        __syncthreads();
        if (t < 8) {
            float s = redw[0][t][0] + redw[1][t][0] + redw[2][t][0] + redw[3][t][0];
            float q = redw[0][t][1] + redw[1][t][1] + redw[2][t][1] + redw[3][t][1];
            float mean = s * (1.f / C);
            float var = q * (1.f / C) - mean * mean;
            mv[t][0] = mean; mv[t][1] = rsqrtf(var + 1e-5f);
        }
        __syncthreads();
        #pragma unroll
        for (int r = 0; r < 8; r++) {
            int grow = row0 + g * 8 + r;
            ws[X3o + (size_t)grow * C + t] = (rv[r] - mv[r][0]) * mv[r][1];
        }
        __syncthreads();
    }
}

// ---------------- masked view-mean + output0 ----------------
__global__ __launch_bounds__(256) void k_fuse(const int* maskin, float* ws, float* out) {
    int row = blockIdx.x, j = threadIdx.x;
    int b = row / P, p = row % P;
    float s = 0.f, cnt = 0.f;
    for (int v = 0; v < V; v++) {
        bool mk = (maskin[(b * P + p) * V + v] > 0) && (ws[MFLAG + b * V + v] > 0.5f);
        if (mk) {
            s += ws[X3o + ((size_t)((b * V + v) * P + p)) * C + j];
            cnt += 1.f;
        }
    }
    float f = s / (cnt + 1e-4f);
    ws[FUSEDo + (size_t)row * C + j] = f;
    out[O0 + ((size_t)b * C + j) * P + p] = f;
}

// ---------------- pred head + BEV outputs ----------------
__global__ __launch_bounds__(256) void k_pred(const float* w1, const float* b1, const float* w2, const float* b2,
                                              const float* qposin, float* ws, float* out) {
    int row = blockIdx.x, j = threadIdx.x;
    __shared__ __align__(16) float in[C];
    __shared__ float red[256];
    __shared__ float cen[4];
    in[j] = ws[FUSEDo + (size_t)row * C + j];
    __syncthreads();
    float h = fmaxf(b1[j] + dotK(in, w1, j, C, C), 0.f);
    for (int i = 0; i < 3; i++) {
        float s = blockReduceSum(h * w2[j * 3 + i], red);
        if (j == 0) cen[i] = s + b2[i] + qposin[row * 3 + i];
    }
    if (j == 0) {
        float c0 = cen[0], c1 = cen[1], c2 = cen[2];
        float cx = (c0 + 54.f) / 108.f * 135.f;
        float cy = (c1 + 54.f) / 108.f * 135.f;
        int b = row / P, p = row % P;
        out[O1 + (size_t)row * 3 + 0] = c0;
        out[O1 + (size_t)row * 3 + 1] = c1;
        out[O1 + (size_t)row * 3 + 2] = c2;
        out[O2 + (size_t)row * 2 + 0] = cx;
        out[O2 + (size_t)row * 2 + 1] = cy;
        out[O3 + (size_t)b * 2 * P + 0 * P + p] = cx;
        out[O3 + (size_t)b * 2 * P + 1 * P + p] = cy;
        out[O4 + (size_t)b * P + p] = c2;
    }
}

extern "C" void kernel_launch(void* const* d_in, const int* in_sizes, int n_in,
                              void* d_out, int out_size, void* d_ws, size_t ws_size,
                              hipStream_t stream) {
    const float* qfeat  = (const float*)d_in[0];
    const float* qposin = (const float*)d_in[1];
    const int*   maskin = (const int*)d_in[2];
    const float* feats  = (const float*)d_in[3];
    const float* npos   = (const float*)d_in[4];
    const float* rt     = (const float*)d_in[5];
    const float* l2cr   = (const float*)d_in[6];
    const float* l2ct   = (const float*)d_in[7];
    const float* qp_w1 = (const float*)d_in[8],  * qp_b1 = (const float*)d_in[9];
    const float* qp_w2 = (const float*)d_in[10], * qp_b2 = (const float*)d_in[11];
    const float* kp_w1 = (const float*)d_in[12], * kp_b1 = (const float*)d_in[13];
    const float* kp_w2 = (const float*)d_in[14], * kp_b2 = (const float*)d_in[15];
    const float* sa_wq = (const float*)d_in[16], * sa_wk = (const float*)d_in[17];
    const float* sa_wv = (const float*)d_in[18], * sa_wo = (const float*)d_in[19];
    const float* dv_w  = (const float*)d_in[20];
    const float* doffw = (const float*)d_in[21], * doffb = (const float*)d_in[22];
    const float* dattw = (const float*)d_in[23], * dattb = (const float*)d_in[24];
    const float* doutw = (const float*)d_in[25];
    const float* f_w1  = (const float*)d_in[26], * f_b1 = (const float*)d_in[27];
    const float* f_w2  = (const float*)d_in[28], * f_b2 = (const float*)d_in[29];
    const float* p_w1  = (const float*)d_in[30], * p_b1 = (const float*)d_in[31];
    const float* p_w2  = (const float*)d_in[32], * p_b2 = (const float*)d_in[33];

    float* ws = (float*)d_ws;
    bf16* vals = (bf16*)((char*)d_ws + VALS_BYTE_OFF);
    bf16* wb = vals + VALS_ELEMS;
    bf16* hidb = wb + HIDB_O;
    float* out = (float*)d_out;

    k_setup<<<1, 64, 0, stream>>>(rt, l2cr, l2ct, maskin, ws);
    k_wprep_all<<<3456, 256, 0, stream>>>(kp_w2, dv_w, sa_wo, doutw, doffw, dattw,
                                          sa_wq, sa_wk, sa_wv, f_w1, f_w2, wb);
    k_qpos<<<BP, 256, 0, stream>>>(qfeat, qposin, qp_w1, qp_b1, qp_w2, qp_b2, ws);
    k_qkv_mfma<<<BP / 16, 256, 0, stream>>>(wb + QKVT_O, ws);
    k_logits<<<B * HH * P, 256, 0, stream>>>(ws);
    k_sattn<<<B * V * HH * P, 256, 0, stream>>>(maskin, ws);
    k_lngemm<<<BVP / 32, 256, 0, stream>>>(wb + WOT_O, ws, SAo, Xo, 1, X1o);
    k_ref<<<(BVP + 255) / 256, 256, 0, stream>>>(qposin, rt, ws);
    k_offaw_mfma<<<BVP / 32, 256, 0, stream>>>(wb + OAWT_O, doffb, dattb, ws);
    k_vals_mfma<<<dim3(NVT, BV), 256, 0, stream>>>(npos, feats, kp_w1, kp_b1, kp_b2,
                                                   wb + KW2T_O, wb + DVWT_O, ws, vals);
    k_sample<<<BVP, 256, 0, stream>>>(ws, vals, ws);
    k_lngemm<<<BVP / 32, 256, 0, stream>>>(wb + DOUTT_O, ws, OUTSo, X1o, 0, X2o);
    k_ffn1<<<dim3(BVP / 32, 2), 256, 0, stream>>>(wb + W1T_O, f_b1, ws, hidb);
    k_ffn2<<<BVP / 32, 256, 0, stream>>>(wb + W2T_O, f_b2, hidb, ws);
    k_fuse<<<BP, 256, 0, stream>>>(maskin, ws, out);
    k_pred<<<BP, 256, 0, stream>>>(p_w1, p_b1, p_w2, p_b2, qposin, ws, out);
}